// Round 5
// baseline (1421.040 us; speedup 1.0000x reference)
//
#include <hip/hip_runtime.h>
#include <stdint.h>

// Problem constants
#define Bn   2
#define Sn   4096
#define NQn  576
#define Hn   32
#define HDn  128
#define HIDn 4096

typedef unsigned short bfu;  // raw bf16 bits
typedef short short8 __attribute__((ext_vector_type(8)));
typedef float f32x4 __attribute__((ext_vector_type(4)));

__device__ __forceinline__ bfu f2b(float f) {
  uint32_t x = __builtin_bit_cast(uint32_t, f);
  return (bfu)((x + 0x7fffu + ((x >> 16) & 1u)) >> 16);  // RNE
}

__device__ __forceinline__ void gload16(const void* g, void* l) {
  // async global->LDS, 16B per lane; LDS dest = wave-uniform base + lane*16
  __builtin_amdgcn_global_load_lds(
      (const __attribute__((address_space(1))) uint32_t*)g,
      (__attribute__((address_space(3))) uint32_t*)l, 16, 0, 0);
}

// ---------------- cast f32 -> bf16 (vectorized: 2x float4 in, 16B out) ---------
__global__ void cast_f32_bf16(const float* __restrict__ in, bfu* __restrict__ out,
                              int n8) {
  int i = blockIdx.x * 256 + threadIdx.x;
  if (i >= n8) return;
  const float4* in4 = (const float4*)in;
  float4 a = in4[2 * i], c = in4[2 * i + 1];
  short8 v;
  v[0] = (short)f2b(a.x); v[1] = (short)f2b(a.y);
  v[2] = (short)f2b(a.z); v[3] = (short)f2b(a.w);
  v[4] = (short)f2b(c.x); v[5] = (short)f2b(c.y);
  v[6] = (short)f2b(c.z); v[7] = (short)f2b(c.w);
  ((short8*)out)[i] = v;
}

// ======== 256^2-tile deep-pipelined GEMM: C[M][N] = A[M][K] @ Bm[N][K]^T =======
// R4 post-mortem: m97-structure 128^2 kernel sits at its known ~850TF ceiling
// (MfmaUtil 37%, 3.4e7 bank conflicts). This kernel applies the T2/T3/T4/T5
// stack: 512 thr = 8 waves (2M x 4N), per-wave 128x64 output, BK=32.
// - LDS ring of 4 slots (A+B each 256x32 bf16 = 16KB/slot, 128KB total).
//   While computing tile t (slot t&3), stage tile t+3 into slot (t+3)&3 =
//   slot of tile t-1 (freed at the end-of-(t-1) barrier) -> no overwrite
//   hazard by construction; ~3 tiles (~900cy) of prefetch lead >= HBM latency.
// - Counted vmcnt(8) (= 2 tiles x 4 loads/wave in flight) at each tile
//   boundary; vmcnt(0) only at the last two boundaries (provable drain).
//   RAW s_barrier everywhere -- __syncthreads() would inject vmcnt(0) and
//   recreate the m97 stall.
// - 2 phases/tile, 16 MFMA each, setprio(1) around the cluster (T5),
//   lgkmcnt(0)+sched_barrier(0) before MFMA (rule #18).
// - Both-sides XOR swizzle byte ^= ((row&3)<<4) on [256][32] tiles: fragment
//   read (16 lanes, same col, rows 0-15) becomes 2-way (= free, m136);
//   16B flip granularity stays compatible with linear global_load_lds dest
//   (rule #21: linear dest + inverse-swizzled SOURCE + swizzled read).
template <int WRITE_BF16>
__global__ __launch_bounds__(512, 2)
void gemm_bt256(const bfu* __restrict__ A, const bfu* __restrict__ Bm,
                void* __restrict__ Cout, int M, int N, int K) {
  __shared__ __align__(16) bfu As[4 * 256 * 32];
  __shared__ __align__(16) bfu Bs[4 * 256 * 32];
  const int tid = threadIdx.x;
  const int wave = tid >> 6, lane = tid & 63;
  const int lr = lane & 15, kq = lane >> 4;
  const int wm = wave >> 2, wn = wave & 3;  // 2 x 4 wave grid
  const long m0 = (long)blockIdx.y * 256, n0 = (long)blockIdx.x * 256;
  const int NT = K >> 5;  // K-tiles of 32

  // per-thread staging sources (two 16B chunks per operand per tile)
  // chunk = rnd*512 + tid ; LDS row j = chunk>>2 ; chunk-in-row c4 = chunk&3 ;
  // global col-chunk = c4 ^ (j&3)  (inverse of the read-side swizzle)
  const bfu* aSrc[2];
  const bfu* bSrc[2];
#pragma unroll
  for (int rnd = 0; rnd < 2; ++rnd) {
    int chunk = rnd * 512 + tid;
    int j = chunk >> 2, c4 = chunk & 3;
    aSrc[rnd] = A + (m0 + j) * (long)K + ((c4 ^ (j & 3)) * 8);
    bSrc[rnd] = Bm + (n0 + j) * (long)K + ((c4 ^ (j & 3)) * 8);
  }
  auto stageA = [&](int u) {
    bfu* base = As + (u & 3) * 8192 + wave * 512;  // elements
#pragma unroll
    for (int rnd = 0; rnd < 2; ++rnd)
      gload16(aSrc[rnd] + u * 32, base + rnd * 4096);
  };
  auto stageB = [&](int u) {
    bfu* base = Bs + (u & 3) * 8192 + wave * 512;
#pragma unroll
    for (int rnd = 0; rnd < 2; ++rnd)
      gload16(bSrc[rnd] + u * 32, base + rnd * 4096);
  };
  auto ldA = [&](int slot, int mf) -> short8 {
    int row = wm * 128 + mf * 16 + lr;
    int off = (row * 64 + kq * 16) ^ ((row & 3) << 4);
    return *(const short8*)((const char*)As + slot * 16384 + off);
  };
  auto ldB = [&](int slot, int nf) -> short8 {
    int row = wn * 64 + nf * 16 + lr;
    int off = (row * 64 + kq * 16) ^ ((row & 3) << 4);
    return *(const short8*)((const char*)Bs + slot * 16384 + off);
  };

  f32x4 acc[8][4] = {};
  // prologue: fill ring slots 0,1,2 ; wait tile0 (leave 8 in flight)
  stageA(0); stageB(0); stageA(1); stageB(1); stageA(2); stageB(2);
  asm volatile("s_waitcnt vmcnt(8)" ::: "memory");
  __builtin_amdgcn_s_barrier();

  short8 af[8], bf[4];
  for (int t = 0; t < NT; ++t) {
    const int slot = t & 3;
    // ---------------- phase A: n-frags 0,1 ----------------
    if (t + 3 < NT) stageA(t + 3);
#pragma unroll
    for (int mf = 0; mf < 8; ++mf) af[mf] = ldA(slot, mf);
    bf[0] = ldB(slot, 0);
    bf[1] = ldB(slot, 1);
    __builtin_amdgcn_s_barrier();
    asm volatile("s_waitcnt lgkmcnt(0)" ::: "memory");
    __builtin_amdgcn_sched_barrier(0);
    __builtin_amdgcn_s_setprio(1);
#pragma unroll
    for (int mf = 0; mf < 8; ++mf) {
      acc[mf][0] = __builtin_amdgcn_mfma_f32_16x16x32_bf16(af[mf], bf[0], acc[mf][0], 0, 0, 0);
      acc[mf][1] = __builtin_amdgcn_mfma_f32_16x16x32_bf16(af[mf], bf[1], acc[mf][1], 0, 0, 0);
    }
    __builtin_amdgcn_s_setprio(0);
    __builtin_amdgcn_s_barrier();
    // ---------------- phase B: n-frags 2,3 ----------------
    if (t + 3 < NT) stageB(t + 3);
    bf[2] = ldB(slot, 2);
    bf[3] = ldB(slot, 3);
    __builtin_amdgcn_s_barrier();
    asm volatile("s_waitcnt lgkmcnt(0)" ::: "memory");
    __builtin_amdgcn_sched_barrier(0);
    __builtin_amdgcn_s_setprio(1);
#pragma unroll
    for (int mf = 0; mf < 8; ++mf) {
      acc[mf][2] = __builtin_amdgcn_mfma_f32_16x16x32_bf16(af[mf], bf[2], acc[mf][2], 0, 0, 0);
      acc[mf][3] = __builtin_amdgcn_mfma_f32_16x16x32_bf16(af[mf], bf[3], acc[mf][3], 0, 0, 0);
    }
    __builtin_amdgcn_s_setprio(0);
    // tile boundary: next tile's loads (issued 3 tiles ago) must be landed.
    // steady state: 8 loads (tiles t+2,t+3) may stay in flight; near the end
    // nothing newer is issued, so drain fully.
    if (t < NT - 2) {
      asm volatile("s_waitcnt vmcnt(8)" ::: "memory");
    } else {
      asm volatile("s_waitcnt vmcnt(0)" ::: "memory");
    }
    __builtin_amdgcn_s_barrier();
  }

  // epilogue: C/D layout col=lane&15, row=(lane>>4)*4+reg
#pragma unroll
  for (int mf = 0; mf < 8; ++mf)
#pragma unroll
    for (int nf = 0; nf < 4; ++nf)
#pragma unroll
      for (int r = 0; r < 4; ++r) {
        long row = m0 + wm * 128 + mf * 16 + kq * 4 + r;
        long col = n0 + wn * 64 + nf * 16 + lr;
        float v = acc[mf][nf][r];
        if (WRITE_BF16)
          ((bfu*)Cout)[row * N + col] = f2b(v);
        else
          ((float*)Cout)[row * N + col] = v;
      }
}

// ---------------- GEMM: 128^2 m97-style (kept for M=1152 K/V projections) -----
template <int WRITE_BF16>
__global__ __launch_bounds__(256, 2)
void gemm_bt(const bfu* __restrict__ A, const bfu* __restrict__ Bm,
             void* __restrict__ Cout, int M, int N, int K) {
  __shared__ __align__(16) bfu As[128 * 32];
  __shared__ __align__(16) bfu Bs[128 * 32];
  const int tid = threadIdx.x;
  const int wave = tid >> 6, lane = tid & 63;
  const int lr = lane & 15, kq = lane >> 4;
  const int wm = wave >> 1, wn = wave & 1;
  const long m0 = (long)blockIdx.y * 128, n0 = (long)blockIdx.x * 128;

  f32x4 acc[4][4] = {};

  for (int kk = 0; kk < K; kk += 32) {
#pragma unroll
    for (int i = 0; i < 2; ++i) {
      int tt = i * 256 + tid;
      long row = tt >> 2;          // [0,128)
      int col = (tt & 3) * 8;      // {0,8,16,24}
      gload16(A + (m0 + row) * K + kk + col, &As[(i * 256 + wave * 64) * 8]);
      gload16(Bm + (n0 + row) * K + kk + col, &Bs[(i * 256 + wave * 64) * 8]);
    }
    __syncthreads();
    short8 a[4], b[4];
#pragma unroll
    for (int mt = 0; mt < 4; ++mt)
      a[mt] = *(const short8*)&As[(wm * 64 + mt * 16 + lr) * 32 + kq * 8];
#pragma unroll
    for (int nt = 0; nt < 4; ++nt)
      b[nt] = *(const short8*)&Bs[(wn * 64 + nt * 16 + lr) * 32 + kq * 8];
#pragma unroll
    for (int mt = 0; mt < 4; ++mt)
#pragma unroll
      for (int nt = 0; nt < 4; ++nt)
        acc[mt][nt] = __builtin_amdgcn_mfma_f32_16x16x32_bf16(
            a[mt], b[nt], acc[mt][nt], 0, 0, 0);
    __syncthreads();
  }
#pragma unroll
  for (int mt = 0; mt < 4; ++mt)
#pragma unroll
    for (int nt = 0; nt < 4; ++nt)
#pragma unroll
      for (int r = 0; r < 4; ++r) {
        long row = m0 + wm * 64 + mt * 16 + kq * 4 + r;
        long col = n0 + wn * 64 + nt * 16 + lr;
        float v = acc[mt][nt][r];
        if (WRITE_BF16)
          ((bfu*)Cout)[row * N + col] = f2b(v);
        else
          ((float*)Cout)[row * N + col] = v;
      }
}

// ---------------- V transpose: Vb[B*NQ][HID] -> Vt[B*H][HD][NQ] ----------------
__global__ void transpose_v(const bfu* __restrict__ Vb, bfu* __restrict__ Vt) {
  __shared__ bfu t[32][33];
  const int bh = blockIdx.z;            // b*H + h
  const int tq = blockIdx.x;            // nq tile [0,18)
  const int td = blockIdx.y;            // d tile  [0,4)
  const int b = bh >> 5, h = bh & 31;
  const int tx = threadIdx.x & 31, ty = threadIdx.x >> 5;  // ty in [0,8)
  const bfu* src = Vb + ((long)(b * NQn + tq * 32)) * HIDn + h * HDn + td * 32;
#pragma unroll
  for (int i = 0; i < 32; i += 8) t[ty + i][tx] = src[(long)(ty + i) * HIDn + tx];
  __syncthreads();
  bfu* dst = Vt + ((long)bh * HDn + td * 32) * NQn + tq * 32;
#pragma unroll
  for (int i = 0; i < 32; i += 8) dst[(long)(ty + i) * NQn + tx] = t[tx][ty + i];
}

// ---------------- fused attention (R4: K/V LDS-staged, double-buffered) --------
__global__ __launch_bounds__(512, 2)
void attn_kernel(const bfu* __restrict__ Qb, const bfu* __restrict__ Kb,
                 const bfu* __restrict__ Vt, const float* __restrict__ mask,
                 bfu* __restrict__ AO) {
  __shared__ bfu P[64 * 576];      // 73728 B
  __shared__ bfu KV[2][8192];      // 2 x 16KB staging (K tiles, then V tiles)
  __shared__ float red[4][64];     // per-wk partial row sums
  const int swz = blockIdx.x;      // natural order (R2: no XCD chunking!)
  const int h = swz & (Hn - 1);
  const int b = (swz >> 5) & (Bn - 1);
  const int qt0 = swz >> 6;        // [0,64)
  const long q0 = (long)qt0 * 64;
  const int tid = threadIdx.x;
  const int wave = tid >> 6, lane = tid & 63;
  const int lr = lane & 15, kq = lane >> 4;
  const int wk = wave & 3, wq = wave >> 2;
  const float scale = 0.08838834764831845f;  // 1/sqrt(128)

  const bfu* Qbase = Qb + ((long)b * Sn + q0 + wq * 32) * HIDn + h * HDn;
  const bfu* Kblk = Kb + (long)b * NQn * HIDn + h * HDn;
  const bfu* Vblk = Vt + ((long)(b * Hn + h)) * HDn * NQn;
  const float* mbase = mask + ((long)b * Sn + q0 + wq * 32) * NQn + wk * 144;
  char* Pb = (char*)P;

  auto stageK = [&](int mt, int buf) {
#pragma unroll
    for (int i = 0; i < 2; ++i) {
      int c = i * 512 + wave * 64 + lane;
      int j = c >> 4, c16 = c & 15;
      int grow = (j >> 4) * 144 + mt * 16 + (j & 15);
      gload16(Kblk + (long)grow * HIDn + ((c16 ^ (j & 7)) * 8),
              &KV[buf][(i * 512 + wave * 64) * 8]);
    }
  };
  auto stageV = [&](int kt, int buf) {
#pragma unroll
    for (int i = 0; i < 2; ++i) {
      int c = i * 512 + wave * 64 + lane;
      int j = c >> 3, c8 = c & 7;
      gload16(Vblk + (long)j * NQn + kt * 64 + ((c8 ^ (j & 7)) * 8),
              &KV[buf][(i * 512 + wave * 64) * 8]);
    }
  };

  stageK(0, 0);

  short8 qf[2][4];
#pragma unroll
  for (int qt2 = 0; qt2 < 2; ++qt2)
#pragma unroll
    for (int ks = 0; ks < 4; ++ks)
      qf[qt2][ks] =
          *(const short8*)&Qbase[((long)qt2 * 16 + lr) * HIDn + ks * 32 + kq * 8];
  float4 mv[2];
#pragma unroll
  for (int qt2 = 0; qt2 < 2; ++qt2)
    mv[qt2] = *(const float4*)&mbase[((long)qt2 * 16 + lr) * NQn + kq * 4];

  float rsum[2] = {0.f, 0.f};
  for (int mt = 0; mt < 9; ++mt) {
    __syncthreads();  // K(mt) staged + buffers free
    if (mt < 8) stageK(mt + 1, (mt + 1) & 1);
    const int mtn = (mt < 8) ? mt + 1 : mt;
    float4 mvn[2];
#pragma unroll
    for (int qt2 = 0; qt2 < 2; ++qt2)
      mvn[qt2] =
          *(const float4*)&mbase[((long)qt2 * 16 + lr) * NQn + mtn * 16 + kq * 4];

    const char* kb = (const char*)KV[mt & 1];
#pragma unroll
    for (int qt2 = 0; qt2 < 2; ++qt2) {
      const int row = wq * 32 + qt2 * 16 + lr;
      f32x4 sc = {};
#pragma unroll
      for (int ks = 0; ks < 4; ++ks) {
        short8 kf = *(const short8*)(kb + (((wk * 16 + lr) * 256 + ks * 64 + kq * 16) ^
                                           ((lr & 7) << 4)));
        sc = __builtin_amdgcn_mfma_f32_16x16x32_bf16(kf, qf[qt2][ks], sc, 0, 0, 0);
      }
      float p0 = __expf(sc[0] * scale + mv[qt2].x);
      float p1 = __expf(sc[1] * scale + mv[qt2].y);
      float p2 = __expf(sc[2] * scale + mv[qt2].z);
      float p3 = __expf(sc[3] * scale + mv[qt2].w);
      rsum[qt2] += (p0 + p1) + (p2 + p3);
      uint64_t pk = (uint64_t)f2b(p0) | ((uint64_t)f2b(p1) << 16) |
                    ((uint64_t)f2b(p2) << 32) | ((uint64_t)f2b(p3) << 48);
      int off = (row * 1152 + (wk * 288 + mt * 32 + kq * 8)) ^ ((row & 7) << 4);
      *(uint64_t*)(Pb + off) = pk;
    }
    mv[0] = mvn[0];
    mv[1] = mvn[1];
  }
#pragma unroll
  for (int qt2 = 0; qt2 < 2; ++qt2) {
    rsum[qt2] += __shfl_xor(rsum[qt2], 16, 64);
    rsum[qt2] += __shfl_xor(rsum[qt2], 32, 64);
    if (kq == 0) red[wk][wq * 32 + qt2 * 16 + lr] = rsum[qt2];
  }
  __syncthreads();  // P + red complete; KV buffers free

  float inv[2];
#pragma unroll
  for (int qt = 0; qt < 2; ++qt) {
    int row = wq * 32 + qt * 16 + lr;
    inv[qt] = 1.0f / ((red[0][row] + red[1][row]) + (red[2][row] + red[3][row]));
  }

  const int wd = wk;
  stageV(0, 0);
  f32x4 o[2][2] = {};
  for (int kt = 0; kt < 9; ++kt) {
    __syncthreads();  // V(kt) staged
    if (kt < 8) stageV(kt + 1, (kt + 1) & 1);
    const char* vb = (const char*)KV[kt & 1];
#pragma unroll
    for (int sub = 0; sub < 2; ++sub) {
      const int ks = kt * 2 + sub;
      short8 vf[2], pf[2];
#pragma unroll
      for (int dt = 0; dt < 2; ++dt)
        vf[dt] = *(const short8*)(vb + (((wd * 32 + dt * 16 + lr) * 128 + sub * 64 +
                                         kq * 16) ^
                                        ((lr & 7) << 4)));
#pragma unroll
      for (int qt = 0; qt < 2; ++qt) {
        int row = wq * 32 + qt * 16 + lr;
        int off = (row * 1152 + (ks * 64 + kq * 16)) ^ ((row & 7) << 4);
        pf[qt] = *(const short8*)(Pb + off);
      }
#pragma unroll
      for (int qt = 0; qt < 2; ++qt)
#pragma unroll
        for (int dt = 0; dt < 2; ++dt)
          o[qt][dt] = __builtin_amdgcn_mfma_f32_16x16x32_bf16(vf[dt], pf[qt],
                                                              o[qt][dt], 0, 0, 0);
    }
  }
#pragma unroll
  for (int qt = 0; qt < 2; ++qt) {
    const long qrow = (long)b * Sn + q0 + wq * 32 + qt * 16 + lr;
    const float iv = inv[qt];
#pragma unroll
    for (int dt = 0; dt < 2; ++dt) {
      uint64_t pk = (uint64_t)f2b(o[qt][dt][0] * iv) |
                    ((uint64_t)f2b(o[qt][dt][1] * iv) << 16) |
                    ((uint64_t)f2b(o[qt][dt][2] * iv) << 32) |
                    ((uint64_t)f2b(o[qt][dt][3] * iv) << 48);
      *(uint64_t*)&AO[qrow * HIDn + h * HDn + wd * 32 + dt * 16 + kq * 4] = pk;
    }
  }
}

// ------------------------------- launcher --------------------------------------
extern "C" void kernel_launch(void* const* d_in, const int* in_sizes, int n_in,
                              void* d_out, int out_size, void* d_ws, size_t ws_size,
                              hipStream_t stream) {
  const float* hs = (const float*)d_in[0];
  const float* bp = (const float*)d_in[1];
  const float* mask = (const float*)d_in[2];
  const float* Wq = (const float*)d_in[3];
  const float* Wk = (const float*)d_in[4];
  const float* Wv = (const float*)d_in[5];
  const float* Wo = (const float*)d_in[6];
  float* out = (float*)d_out;

  const long M1 = (long)Bn * Sn;   // 8192
  const long M2 = (long)Bn * NQn;  // 1152
  char* ws = (char*)d_ws;
  bfu* hb = (bfu*)(ws + 0);                  // 67,108,864  (also AO)
  bfu* bb = (bfu*)(ws + 67108864);           //  9,437,184
  bfu* w1 = (bfu*)(ws + 76546048);           // 33,554,432  (Wq, later Wo)
  bfu* wkb = (bfu*)(ws + 110100480);         // 33,554,432
  bfu* wvb = (bfu*)(ws + 143654912);         // 33,554,432
  bfu* Qb = (bfu*)(ws + 177209344);          // 67,108,864
  bfu* Kb = (bfu*)(ws + 244318208);          //  9,437,184
  bfu* Vb = (bfu*)(ws + 253755392);          //  9,437,184
  bfu* Vt = (bfu*)(ws + 263192576);          //  9,437,184  -> total 272,629,760

  auto cast = [&](const float* src, bfu* dst, long n) {
    int n8 = (int)(n / 8);
    cast_f32_bf16<<<dim3((n8 + 255) / 256), dim3(256), 0, stream>>>(src, dst, n8);
  };
  cast(hs, hb, M1 * HIDn);
  cast(bp, bb, M2 * HIDn);
  cast(Wq, w1, (long)HIDn * HIDn);
  cast(Wk, wkb, (long)HIDn * HIDn);
  cast(Wv, wvb, (long)HIDn * HIDn);

  gemm_bt256<1><<<dim3(HIDn / 256, M1 / 256), dim3(512), 0, stream>>>(
      hb, w1, Qb, (int)M1, HIDn, HIDn);
  gemm_bt<1><<<dim3(HIDn / 128, M2 / 128), dim3(256), 0, stream>>>(
      bb, wkb, Kb, (int)M2, HIDn, HIDn);
  gemm_bt<1><<<dim3(HIDn / 128, M2 / 128), dim3(256), 0, stream>>>(
      bb, wvb, Vb, (int)M2, HIDn, HIDn);

  cast(Wo, w1, (long)HIDn * HIDn);  // w1 slot free after Q-proj
  transpose_v<<<dim3(NQn / 32, HDn / 32, Bn * Hn), dim3(256), 0, stream>>>(Vb, Vt);

  attn_kernel<<<dim3((Sn / 64) * Bn * Hn), dim3(512), 0, stream>>>(
      Qb, Kb, Vt, mask, hb /*AO aliases hb*/);

  gemm_bt256<0><<<dim3(HIDn / 256, M1 / 256), dim3(512), 0, stream>>>(
      hb, w1, out, (int)M1, HIDn, HIDn);
}

// Round 7
// 1151.875 us; speedup vs baseline: 1.2337x; 1.2337x over previous
//
#include <hip/hip_runtime.h>
#include <stdint.h>

// Problem constants
#define Bn   2
#define Sn   4096
#define NQn  576
#define Hn   32
#define HDn  128
#define HIDn 4096

typedef unsigned short bfu;  // raw bf16 bits
typedef short short8 __attribute__((ext_vector_type(8)));
typedef float f32x4 __attribute__((ext_vector_type(4)));

__device__ __forceinline__ bfu f2b(float f) {
  uint32_t x = __builtin_bit_cast(uint32_t, f);
  return (bfu)((x + 0x7fffu + ((x >> 16) & 1u)) >> 16);  // RNE
}

__device__ __forceinline__ void gload16(const void* g, void* l) {
  // async global->LDS, 16B per lane; LDS dest = wave-uniform base + lane*16
  __builtin_amdgcn_global_load_lds(
      (const __attribute__((address_space(1))) uint32_t*)g,
      (__attribute__((address_space(3))) uint32_t*)l, 16, 0, 0);
}

// ---------------- cast f32 -> bf16 (vectorized: 2x float4 in, 16B out) ---------
__global__ void cast_f32_bf16(const float* __restrict__ in, bfu* __restrict__ out,
                              int n8) {
  int i = blockIdx.x * 256 + threadIdx.x;
  if (i >= n8) return;
  const float4* in4 = (const float4*)in;
  float4 a = in4[2 * i], c = in4[2 * i + 1];
  short8 v;
  v[0] = (short)f2b(a.x); v[1] = (short)f2b(a.y);
  v[2] = (short)f2b(a.z); v[3] = (short)f2b(a.w);
  v[4] = (short)f2b(c.x); v[5] = (short)f2b(c.y);
  v[6] = (short)f2b(c.z); v[7] = (short)f2b(c.w);
  ((short8*)out)[i] = v;
}

// ======== 256^2 4-phase GEMM (m201-style): C = A[M][K] @ Bm[N][K]^T ===========
// R6 post-mortem (correctness bug): staging halves are ROW-halves (h0=rows
// 0-127, h1=128-255), but the old wave grid read rows wm*128+mf*16 /
// wn*64+nf*16 -> waves wm=1 / wn>=2 consumed h1 data in P0, which the vmcnt
// ledger only guarantees by P1/P2-close. 6 of 8 waves raced the in-flight
// global_load_lds. FIX: per-wave fragment rows now straddle the halves:
//   A row(mf) = (mf>>2)*128 + wm*64 + (mf&3)*16   (mf 0-3 in h0, 4-7 in h1)
//   B row(nf) = (nf>>1)*128 + wn*32 + (nf&1)*16   (nf 0-1 in h0, 2-3 in h1)
// so Q0=Ah0*Bh0, Q1=Ah0*Bh1, Q2=Ah1*Bh1, Q3=Ah1*Bh0 for EVERY wave -- reads
// always behind the ledger. Schedule/ledger unchanged from R6:
//   stages (t+1): P0:Ah0 P1:Bh0 P2:Bh1 P3:Ah1 ; vmcnt(4) at close of P0
//   (drains Bh1(t)), P1 (Ah1(t)), P3 (Ah0/Bh0(t+1)); peeled tail 4->2->0.
// BK=64 (128B rows, 8 chunks), both-sides XOR byte^=((row&7)<<4).
// Raw s_barrier only; lgkmcnt(0)+sched_barrier(0) per rule #18; setprio (T5).
template <int WRITE_BF16>
__global__ __launch_bounds__(512, 2)
void gemm_bt256(const bfu* __restrict__ A, const bfu* __restrict__ Bm,
                void* __restrict__ Cout, int M, int N, int K) {
  __shared__ __align__(16) bfu Asm[2][256 * 64];  // 32KB per buffer
  __shared__ __align__(16) bfu Bsm[2][256 * 64];
  const int tid = threadIdx.x;
  const int wave = tid >> 6, lane = tid & 63;
  const int lr = lane & 15, kq = lane >> 4;
  const int wm = wave >> 2, wn = wave & 3;  // 2 x 4 wave grid
  const long m0 = (long)blockIdx.y * 256, n0 = (long)blockIdx.x * 256;
  const int NT = K >> 6;  // K-tiles of 64

  // per-thread staging sources. chunk c = rnd*512+tid ; row j=c>>3 (0..127),
  // chunk-in-row c8=c&7 ; global col chunk = c8 ^ (j&7) (inverse of read swz).
  const int c0j = tid >> 3, c0c = tid & 7;
  const int c1j = (512 + tid) >> 3, c1c = tid & 7;  // (512+tid)&7 == tid&7
  const bfu* aSrc0 = A + (m0 + c0j) * (long)K + ((c0c ^ (c0j & 7)) * 8);
  const bfu* aSrc1 = A + (m0 + c1j) * (long)K + ((c1c ^ (c1j & 7)) * 8);
  const bfu* bSrc0 = Bm + (n0 + c0j) * (long)K + ((c0c ^ (c0j & 7)) * 8);
  const bfu* bSrc1 = Bm + (n0 + c1j) * (long)K + ((c1c ^ (c1j & 7)) * 8);

  // stage half-tile `half` (128 rows) of K-tile t into buffer buf
  auto stageA = [&](int t, int buf, int half) {
    long koff = (long)t * 64 + (long)half * 128 * K;
    gload16(aSrc0 + koff, &Asm[buf][half * 8192 + (wave * 64) * 8]);
    gload16(aSrc1 + koff, &Asm[buf][half * 8192 + (512 + wave * 64) * 8]);
  };
  auto stageB = [&](int t, int buf, int half) {
    long koff = (long)t * 64 + (long)half * 128 * K;
    gload16(bSrc0 + koff, &Bsm[buf][half * 8192 + (wave * 64) * 8]);
    gload16(bSrc1 + koff, &Bsm[buf][half * 8192 + (512 + wave * 64) * 8]);
  };
  // fragment reads (swizzled): ks in {0,1} = K-half of the 64-wide tile.
  // Row formulas straddle halves so quadrant q touches only half (q-gated).
  auto ldsA = [&](int buf, int mf, int ks) -> short8 {
    int row = (mf >> 2) * 128 + wm * 64 + (mf & 3) * 16 + lr;
    int off = (row * 128 + ks * 64 + kq * 16) ^ ((row & 7) << 4);
    return *(const short8*)((const char*)Asm[buf] + off);
  };
  auto ldsB = [&](int buf, int nf, int ks) -> short8 {
    int row = (nf >> 1) * 128 + wn * 32 + (nf & 1) * 16 + lr;
    int off = (row * 128 + ks * 64 + kq * 16) ^ ((row & 7) << 4);
    return *(const short8*)((const char*)Bsm[buf] + off);
  };

  f32x4 acc[8][4] = {};
  short8 aA[4][2], bB0[2][2], bB1[2][2];

#define MFMA_Q(MFBASE, NFBASE, BARR)                                            \
  __builtin_amdgcn_s_barrier();                                                 \
  asm volatile("s_waitcnt lgkmcnt(0)" ::: "memory");                            \
  __builtin_amdgcn_sched_barrier(0);                                            \
  __builtin_amdgcn_s_setprio(1);                                                \
  _Pragma("unroll") for (int mf = 0; mf < 4; ++mf)                              \
      _Pragma("unroll") for (int ks = 0; ks < 2; ++ks)                          \
      _Pragma("unroll") for (int nf = 0; nf < 2; ++nf)                          \
      acc[MFBASE + mf][NFBASE + nf] = __builtin_amdgcn_mfma_f32_16x16x32_bf16(  \
          aA[mf][ks], BARR[nf][ks], acc[MFBASE + mf][NFBASE + nf], 0, 0, 0);    \
  __builtin_amdgcn_s_setprio(0);

  // prologue: stage tile 0 in ledger order Ah0,Bh0,Bh1,Ah1
  stageA(0, 0, 0); stageB(0, 0, 0); stageB(0, 0, 1); stageA(0, 0, 1);
  asm volatile("s_waitcnt vmcnt(4)" ::: "memory");  // Ah0,Bh0 landed
  __builtin_amdgcn_s_barrier();

  for (int t = 0; t < NT - 1; ++t) {
    const int buf = t & 1, nbuf = buf ^ 1;
    // ---- P0: read Ah0 frags + Bh0 frags; stage Ah0(t+1); MFMA Q0 ----
#pragma unroll
    for (int mf = 0; mf < 4; ++mf) {
      aA[mf][0] = ldsA(buf, mf, 0);
      aA[mf][1] = ldsA(buf, mf, 1);
    }
#pragma unroll
    for (int nf = 0; nf < 2; ++nf) {
      bB0[nf][0] = ldsB(buf, nf, 0);
      bB0[nf][1] = ldsB(buf, nf, 1);
    }
    stageA(t + 1, nbuf, 0);
    MFMA_Q(0, 0, bB0)
    asm volatile("s_waitcnt vmcnt(4)" ::: "memory");  // drain Bh1(t)
    __builtin_amdgcn_s_barrier();
    // ---- P1: read Bh1 frags; stage Bh0(t+1); MFMA Q1 ----
#pragma unroll
    for (int nf = 0; nf < 2; ++nf) {
      bB1[nf][0] = ldsB(buf, 2 + nf, 0);
      bB1[nf][1] = ldsB(buf, 2 + nf, 1);
    }
    stageB(t + 1, nbuf, 0);
    MFMA_Q(0, 2, bB1)
    asm volatile("s_waitcnt vmcnt(4)" ::: "memory");  // drain Ah1(t)
    __builtin_amdgcn_s_barrier();
    // ---- P2: read Ah1 frags; stage Bh1(t+1); MFMA Q2 ----
#pragma unroll
    for (int mf = 0; mf < 4; ++mf) {
      aA[mf][0] = ldsA(buf, 4 + mf, 0);
      aA[mf][1] = ldsA(buf, 4 + mf, 1);
    }
    stageB(t + 1, nbuf, 1);
    MFMA_Q(4, 2, bB1)
    __builtin_amdgcn_s_barrier();
    // ---- P3: re-read Bh0 frags; stage Ah1(t+1); MFMA Q3 ----
#pragma unroll
    for (int nf = 0; nf < 2; ++nf) {
      bB0[nf][0] = ldsB(buf, nf, 0);
      bB0[nf][1] = ldsB(buf, nf, 1);
    }
    stageA(t + 1, nbuf, 1);
    MFMA_Q(4, 0, bB0)
    asm volatile("s_waitcnt vmcnt(4)" ::: "memory");  // drain Ah0,Bh0(t+1)
    __builtin_amdgcn_s_barrier();
  }
  // ---- peeled last tile (no staging; counted drains 4 -> 2 -> 0) ----
  {
    const int buf = (NT - 1) & 1;
#pragma unroll
    for (int mf = 0; mf < 4; ++mf) {
      aA[mf][0] = ldsA(buf, mf, 0);
      aA[mf][1] = ldsA(buf, mf, 1);
    }
#pragma unroll
    for (int nf = 0; nf < 2; ++nf) {
      bB0[nf][0] = ldsB(buf, nf, 0);
      bB0[nf][1] = ldsB(buf, nf, 1);
    }
    MFMA_Q(0, 0, bB0)
    asm volatile("s_waitcnt vmcnt(2)" ::: "memory");  // drain Bh1
    __builtin_amdgcn_s_barrier();
#pragma unroll
    for (int nf = 0; nf < 2; ++nf) {
      bB1[nf][0] = ldsB(buf, 2 + nf, 0);
      bB1[nf][1] = ldsB(buf, 2 + nf, 1);
    }
    MFMA_Q(0, 2, bB1)
    asm volatile("s_waitcnt vmcnt(0)" ::: "memory");  // drain Ah1
    __builtin_amdgcn_s_barrier();
#pragma unroll
    for (int mf = 0; mf < 4; ++mf) {
      aA[mf][0] = ldsA(buf, 4 + mf, 0);
      aA[mf][1] = ldsA(buf, 4 + mf, 1);
    }
    MFMA_Q(4, 2, bB1)
    __builtin_amdgcn_s_barrier();
#pragma unroll
    for (int nf = 0; nf < 2; ++nf) {
      bB0[nf][0] = ldsB(buf, nf, 0);
      bB0[nf][1] = ldsB(buf, nf, 1);
    }
    MFMA_Q(4, 0, bB0)
  }
#undef MFMA_Q

  // epilogue: C/D layout col=lane&15, row=(lane>>4)*4+reg; fragment->global
  // mapping mirrors ldsA/ldsB row formulas (half-straddling wave grid).
#pragma unroll
  for (int mf = 0; mf < 8; ++mf)
#pragma unroll
    for (int nf = 0; nf < 4; ++nf)
#pragma unroll
      for (int r = 0; r < 4; ++r) {
        long row = m0 + (mf >> 2) * 128 + wm * 64 + (mf & 3) * 16 + kq * 4 + r;
        long col = n0 + (nf >> 1) * 128 + wn * 32 + (nf & 1) * 16 + lr;
        float v = acc[mf][nf][r];
        if (WRITE_BF16)
          ((bfu*)Cout)[row * N + col] = f2b(v);
        else
          ((float*)Cout)[row * N + col] = v;
      }
}

// ---------------- GEMM: 128^2 m97-style (kept for M=1152 K/V projections) -----
template <int WRITE_BF16>
__global__ __launch_bounds__(256, 2)
void gemm_bt(const bfu* __restrict__ A, const bfu* __restrict__ Bm,
             void* __restrict__ Cout, int M, int N, int K) {
  __shared__ __align__(16) bfu As[128 * 32];
  __shared__ __align__(16) bfu Bs[128 * 32];
  const int tid = threadIdx.x;
  const int wave = tid >> 6, lane = tid & 63;
  const int lr = lane & 15, kq = lane >> 4;
  const int wm = wave >> 1, wn = wave & 1;
  const long m0 = (long)blockIdx.y * 128, n0 = (long)blockIdx.x * 128;

  f32x4 acc[4][4] = {};

  for (int kk = 0; kk < K; kk += 32) {
#pragma unroll
    for (int i = 0; i < 2; ++i) {
      int tt = i * 256 + tid;
      long row = tt >> 2;          // [0,128)
      int col = (tt & 3) * 8;      // {0,8,16,24}
      gload16(A + (m0 + row) * K + kk + col, &As[(i * 256 + wave * 64) * 8]);
      gload16(Bm + (n0 + row) * K + kk + col, &Bs[(i * 256 + wave * 64) * 8]);
    }
    __syncthreads();
    short8 a[4], b[4];
#pragma unroll
    for (int mt = 0; mt < 4; ++mt)
      a[mt] = *(const short8*)&As[(wm * 64 + mt * 16 + lr) * 32 + kq * 8];
#pragma unroll
    for (int nt = 0; nt < 4; ++nt)
      b[nt] = *(const short8*)&Bs[(wn * 64 + nt * 16 + lr) * 32 + kq * 8];
#pragma unroll
    for (int mt = 0; mt < 4; ++mt)
#pragma unroll
      for (int nt = 0; nt < 4; ++nt)
        acc[mt][nt] = __builtin_amdgcn_mfma_f32_16x16x32_bf16(
            a[mt], b[nt], acc[mt][nt], 0, 0, 0);
    __syncthreads();
  }
#pragma unroll
  for (int mt = 0; mt < 4; ++mt)
#pragma unroll
    for (int nt = 0; nt < 4; ++nt)
#pragma unroll
      for (int r = 0; r < 4; ++r) {
        long row = m0 + wm * 64 + mt * 16 + kq * 4 + r;
        long col = n0 + wn * 64 + nt * 16 + lr;
        float v = acc[mt][nt][r];
        if (WRITE_BF16)
          ((bfu*)Cout)[row * N + col] = f2b(v);
        else
          ((float*)Cout)[row * N + col] = v;
      }
}

// ---------------- V transpose: Vb[B*NQ][HID] -> Vt[B*H][HD][NQ] ----------------
__global__ void transpose_v(const bfu* __restrict__ Vb, bfu* __restrict__ Vt) {
  __shared__ bfu t[32][33];
  const int bh = blockIdx.z;            // b*H + h
  const int tq = blockIdx.x;            // nq tile [0,18)
  const int td = blockIdx.y;            // d tile  [0,4)
  const int b = bh >> 5, h = bh & 31;
  const int tx = threadIdx.x & 31, ty = threadIdx.x >> 5;  // ty in [0,8)
  const bfu* src = Vb + ((long)(b * NQn + tq * 32)) * HIDn + h * HDn + td * 32;
#pragma unroll
  for (int i = 0; i < 32; i += 8) t[ty + i][tx] = src[(long)(ty + i) * HIDn + tx];
  __syncthreads();
  bfu* dst = Vt + ((long)bh * HDn + td * 32) * NQn + tq * 32;
#pragma unroll
  for (int i = 0; i < 32; i += 8) dst[(long)(ty + i) * NQn + tx] = t[tx][ty + i];
}

// ---------------- fused attention (R4: K/V LDS-staged, double-buffered) --------
__global__ __launch_bounds__(512, 2)
void attn_kernel(const bfu* __restrict__ Qb, const bfu* __restrict__ Kb,
                 const bfu* __restrict__ Vt, const float* __restrict__ mask,
                 bfu* __restrict__ AO) {
  __shared__ bfu P[64 * 576];      // 73728 B
  __shared__ bfu KV[2][8192];      // 2 x 16KB staging (K tiles, then V tiles)
  __shared__ float red[4][64];     // per-wk partial row sums
  const int swz = blockIdx.x;      // natural order (R2: no XCD chunking!)
  const int h = swz & (Hn - 1);
  const int b = (swz >> 5) & (Bn - 1);
  const int qt0 = swz >> 6;        // [0,64)
  const long q0 = (long)qt0 * 64;
  const int tid = threadIdx.x;
  const int wave = tid >> 6, lane = tid & 63;
  const int lr = lane & 15, kq = lane >> 4;
  const int wk = wave & 3, wq = wave >> 2;
  const float scale = 0.08838834764831845f;  // 1/sqrt(128)

  const bfu* Qbase = Qb + ((long)b * Sn + q0 + wq * 32) * HIDn + h * HDn;
  const bfu* Kblk = Kb + (long)b * NQn * HIDn + h * HDn;
  const bfu* Vblk = Vt + ((long)(b * Hn + h)) * HDn * NQn;
  const float* mbase = mask + ((long)b * Sn + q0 + wq * 32) * NQn + wk * 144;
  char* Pb = (char*)P;

  auto stageK = [&](int mt, int buf) {
#pragma unroll
    for (int i = 0; i < 2; ++i) {
      int c = i * 512 + wave * 64 + lane;
      int j = c >> 4, c16 = c & 15;
      int grow = (j >> 4) * 144 + mt * 16 + (j & 15);
      gload16(Kblk + (long)grow * HIDn + ((c16 ^ (j & 7)) * 8),
              &KV[buf][(i * 512 + wave * 64) * 8]);
    }
  };
  auto stageV = [&](int kt, int buf) {
#pragma unroll
    for (int i = 0; i < 2; ++i) {
      int c = i * 512 + wave * 64 + lane;
      int j = c >> 3, c8 = c & 7;
      gload16(Vblk + (long)j * NQn + kt * 64 + ((c8 ^ (j & 7)) * 8),
              &KV[buf][(i * 512 + wave * 64) * 8]);
    }
  };

  stageK(0, 0);

  short8 qf[2][4];
#pragma unroll
  for (int qt2 = 0; qt2 < 2; ++qt2)
#pragma unroll
    for (int ks = 0; ks < 4; ++ks)
      qf[qt2][ks] =
          *(const short8*)&Qbase[((long)qt2 * 16 + lr) * HIDn + ks * 32 + kq * 8];
  float4 mv[2];
#pragma unroll
  for (int qt2 = 0; qt2 < 2; ++qt2)
    mv[qt2] = *(const float4*)&mbase[((long)qt2 * 16 + lr) * NQn + kq * 4];

  float rsum[2] = {0.f, 0.f};
  for (int mt = 0; mt < 9; ++mt) {
    __syncthreads();  // K(mt) staged + buffers free
    if (mt < 8) stageK(mt + 1, (mt + 1) & 1);
    const int mtn = (mt < 8) ? mt + 1 : mt;
    float4 mvn[2];
#pragma unroll
    for (int qt2 = 0; qt2 < 2; ++qt2)
      mvn[qt2] =
          *(const float4*)&mbase[((long)qt2 * 16 + lr) * NQn + mtn * 16 + kq * 4];

    const char* kb = (const char*)KV[mt & 1];
#pragma unroll
    for (int qt2 = 0; qt2 < 2; ++qt2) {
      const int row = wq * 32 + qt2 * 16 + lr;
      f32x4 sc = {};
#pragma unroll
      for (int ks = 0; ks < 4; ++ks) {
        short8 kf = *(const short8*)(kb + (((wk * 16 + lr) * 256 + ks * 64 + kq * 16) ^
                                           ((lr & 7) << 4)));
        sc = __builtin_amdgcn_mfma_f32_16x16x32_bf16(kf, qf[qt2][ks], sc, 0, 0, 0);
      }
      float p0 = __expf(sc[0] * scale + mv[qt2].x);
      float p1 = __expf(sc[1] * scale + mv[qt2].y);
      float p2 = __expf(sc[2] * scale + mv[qt2].z);
      float p3 = __expf(sc[3] * scale + mv[qt2].w);
      rsum[qt2] += (p0 + p1) + (p2 + p3);
      uint64_t pk = (uint64_t)f2b(p0) | ((uint64_t)f2b(p1) << 16) |
                    ((uint64_t)f2b(p2) << 32) | ((uint64_t)f2b(p3) << 48);
      int off = (row * 1152 + (wk * 288 + mt * 32 + kq * 8)) ^ ((row & 7) << 4);
      *(uint64_t*)(Pb + off) = pk;
    }
    mv[0] = mvn[0];
    mv[1] = mvn[1];
  }
#pragma unroll
  for (int qt2 = 0; qt2 < 2; ++qt2) {
    rsum[qt2] += __shfl_xor(rsum[qt2], 16, 64);
    rsum[qt2] += __shfl_xor(rsum[qt2], 32, 64);
    if (kq == 0) red[wk][wq * 32 + qt2 * 16 + lr] = rsum[qt2];
  }
  __syncthreads();  // P + red complete; KV buffers free

  float inv[2];
#pragma unroll
  for (int qt = 0; qt < 2; ++qt) {
    int row = wq * 32 + qt * 16 + lr;
    inv[qt] = 1.0f / ((red[0][row] + red[1][row]) + (red[2][row] + red[3][row]));
  }

  const int wd = wk;
  stageV(0, 0);
  f32x4 o[2][2] = {};
  for (int kt = 0; kt < 9; ++kt) {
    __syncthreads();  // V(kt) staged
    if (kt < 8) stageV(kt + 1, (kt + 1) & 1);
    const char* vb = (const char*)KV[kt & 1];
#pragma unroll
    for (int sub = 0; sub < 2; ++sub) {
      const int ks = kt * 2 + sub;
      short8 vf[2], pf[2];
#pragma unroll
      for (int dt = 0; dt < 2; ++dt)
        vf[dt] = *(const short8*)(vb + (((wd * 32 + dt * 16 + lr) * 128 + sub * 64 +
                                         kq * 16) ^
                                        ((lr & 7) << 4)));
#pragma unroll
      for (int qt = 0; qt < 2; ++qt) {
        int row = wq * 32 + qt * 16 + lr;
        int off = (row * 1152 + (ks * 64 + kq * 16)) ^ ((row & 7) << 4);
        pf[qt] = *(const short8*)(Pb + off);
      }
#pragma unroll
      for (int qt = 0; qt < 2; ++qt)
#pragma unroll
        for (int dt = 0; dt < 2; ++dt)
          o[qt][dt] = __builtin_amdgcn_mfma_f32_16x16x32_bf16(vf[dt], pf[qt],
                                                              o[qt][dt], 0, 0, 0);
    }
  }
#pragma unroll
  for (int qt = 0; qt < 2; ++qt) {
    const long qrow = (long)b * Sn + q0 + wq * 32 + qt * 16 + lr;
    const float iv = inv[qt];
#pragma unroll
    for (int dt = 0; dt < 2; ++dt) {
      uint64_t pk = (uint64_t)f2b(o[qt][dt][0] * iv) |
                    ((uint64_t)f2b(o[qt][dt][1] * iv) << 16) |
                    ((uint64_t)f2b(o[qt][dt][2] * iv) << 32) |
                    ((uint64_t)f2b(o[qt][dt][3] * iv) << 48);
      *(uint64_t*)&AO[qrow * HIDn + h * HDn + wd * 32 + dt * 16 + kq * 4] = pk;
    }
  }
}

// ------------------------------- launcher --------------------------------------
extern "C" void kernel_launch(void* const* d_in, const int* in_sizes, int n_in,
                              void* d_out, int out_size, void* d_ws, size_t ws_size,
                              hipStream_t stream) {
  const float* hs = (const float*)d_in[0];
  const float* bp = (const float*)d_in[1];
  const float* mask = (const float*)d_in[2];
  const float* Wq = (const float*)d_in[3];
  const float* Wk = (const float*)d_in[4];
  const float* Wv = (const float*)d_in[5];
  const float* Wo = (const float*)d_in[6];
  float* out = (float*)d_out;

  const long M1 = (long)Bn * Sn;   // 8192
  const long M2 = (long)Bn * NQn;  // 1152
  char* ws = (char*)d_ws;
  bfu* hb = (bfu*)(ws + 0);                  // 67,108,864  (also AO)
  bfu* bb = (bfu*)(ws + 67108864);           //  9,437,184
  bfu* w1 = (bfu*)(ws + 76546048);           // 33,554,432  (Wq, later Wo)
  bfu* wkb = (bfu*)(ws + 110100480);         // 33,554,432
  bfu* wvb = (bfu*)(ws + 143654912);         // 33,554,432
  bfu* Qb = (bfu*)(ws + 177209344);          // 67,108,864
  bfu* Kb = (bfu*)(ws + 244318208);          //  9,437,184
  bfu* Vb = (bfu*)(ws + 253755392);          //  9,437,184
  bfu* Vt = (bfu*)(ws + 263192576);          //  9,437,184  -> total 272,629,760

  auto cast = [&](const float* src, bfu* dst, long n) {
    int n8 = (int)(n / 8);
    cast_f32_bf16<<<dim3((n8 + 255) / 256), dim3(256), 0, stream>>>(src, dst, n8);
  };
  cast(hs, hb, M1 * HIDn);
  cast(bp, bb, M2 * HIDn);
  cast(Wq, w1, (long)HIDn * HIDn);
  cast(Wk, wkb, (long)HIDn * HIDn);
  cast(Wv, wvb, (long)HIDn * HIDn);

  gemm_bt256<1><<<dim3(HIDn / 256, M1 / 256), dim3(512), 0, stream>>>(
      hb, w1, Qb, (int)M1, HIDn, HIDn);
  gemm_bt<1><<<dim3(HIDn / 128, M2 / 128), dim3(256), 0, stream>>>(
      bb, wkb, Kb, (int)M2, HIDn, HIDn);
  gemm_bt<1><<<dim3(HIDn / 128, M2 / 128), dim3(256), 0, stream>>>(
      bb, wvb, Vb, (int)M2, HIDn, HIDn);

  cast(Wo, w1, (long)HIDn * HIDn);  // w1 slot free after Q-proj
  transpose_v<<<dim3(NQn / 32, HDn / 32, Bn * Hn), dim3(256), 0, stream>>>(Vb, Vt);

  attn_kernel<<<dim3((Sn / 64) * Bn * Hn), dim3(512), 0, stream>>>(
      Qb, Kb, Vt, mask, hb /*AO aliases hb*/);

  gemm_bt256<0><<<dim3(HIDn / 256, M1 / 256), dim3(512), 0, stream>>>(
      hb, w1, out, (int)M1, HIDn, HIDn);
}

// Round 8
// 1099.512 us; speedup vs baseline: 1.2924x; 1.0476x over previous
//
#include <hip/hip_runtime.h>
#include <stdint.h>

// Problem constants
#define Bn   2
#define Sn   4096
#define NQn  576
#define Hn   32
#define HDn  128
#define HIDn 4096

typedef unsigned short bfu;  // raw bf16 bits
typedef short short8 __attribute__((ext_vector_type(8)));
typedef float f32x4 __attribute__((ext_vector_type(4)));

__device__ __forceinline__ bfu f2b(float f) {
  uint32_t x = __builtin_bit_cast(uint32_t, f);
  return (bfu)((x + 0x7fffu + ((x >> 16) & 1u)) >> 16);  // RNE
}

__device__ __forceinline__ void gload16(const void* g, void* l) {
  // async global->LDS, 16B per lane; LDS dest = wave-uniform base + lane*16
  __builtin_amdgcn_global_load_lds(
      (const __attribute__((address_space(1))) uint32_t*)g,
      (__attribute__((address_space(3))) uint32_t*)l, 16, 0, 0);
}

// ---------------- cast f32 -> bf16 (vectorized: 2x float4 in, 16B out) ---------
__global__ void cast_f32_bf16(const float* __restrict__ in, bfu* __restrict__ out,
                              int n8) {
  int i = blockIdx.x * 256 + threadIdx.x;
  if (i >= n8) return;
  const float4* in4 = (const float4*)in;
  float4 a = in4[2 * i], c = in4[2 * i + 1];
  short8 v;
  v[0] = (short)f2b(a.x); v[1] = (short)f2b(a.y);
  v[2] = (short)f2b(a.z); v[3] = (short)f2b(a.w);
  v[4] = (short)f2b(c.x); v[5] = (short)f2b(c.y);
  v[6] = (short)f2b(c.z); v[7] = (short)f2b(c.w);
  ((short8*)out)[i] = v;
}

// ======== 256^2 whole-tile-pipelined GEMM: C = A[M][K] @ Bm[N][K]^T ===========
// R7 post-mortem: 4-phase lockstep structure ALTERNATED the LDS pipe (2688
// cyc/CU-tile) and MFMA pipe (2483 cyc/CU-tile) -> 5760 cyc walls, MfmaUtil
// 37.7% despite 0 bank conflicts. Fix: whole-tile double-buffer. Stage ALL of
// tile t+1 at the TOP of tile t (prefetch lead = full tile ~2500cy >> 900cy
// HBM latency, so the boundary vmcnt(0) is ~free -- unlike m97's 1-phase
// lead), compute the tile with NO interior barriers/asm (compiler emits
// fine-grained lgkmcnt and pipelines ds_reads under MFMAs), one
// vmcnt(0)+s_barrier per tile. LDS cut 28->24 reads/wave/tile (keep bB0 live).
// Staging, both-sides XOR swizzle (R7-verified, 0 conflicts), half-straddling
// wave geometry, epilogue: byte-identical to R7.
//   A row(mf) = (mf>>2)*128 + wm*64 + (mf&3)*16
//   B row(nf) = (nf>>1)*128 + wn*32 + (nf&1)*16
template <int WRITE_BF16>
__global__ __launch_bounds__(512, 2)
void gemm_bt256(const bfu* __restrict__ A, const bfu* __restrict__ Bm,
                void* __restrict__ Cout, int M, int N, int K) {
  __shared__ __align__(16) bfu Asm[2][256 * 64];  // 32KB per buffer
  __shared__ __align__(16) bfu Bsm[2][256 * 64];
  const int tid = threadIdx.x;
  const int wave = tid >> 6, lane = tid & 63;
  const int lr = lane & 15, kq = lane >> 4;
  const int wm = wave >> 2, wn = wave & 3;  // 2 x 4 wave grid
  const long m0 = (long)blockIdx.y * 256, n0 = (long)blockIdx.x * 256;
  const int NT = K >> 6;  // K-tiles of 64

  // per-thread staging sources. chunk c = rnd*512+tid ; row j=c>>3 (0..127),
  // chunk-in-row c8=c&7 ; global col chunk = c8 ^ (j&7) (inverse of read swz).
  const int c0j = tid >> 3, c0c = tid & 7;
  const int c1j = (512 + tid) >> 3, c1c = tid & 7;  // (512+tid)&7 == tid&7
  const bfu* aSrc0 = A + (m0 + c0j) * (long)K + ((c0c ^ (c0j & 7)) * 8);
  const bfu* aSrc1 = A + (m0 + c1j) * (long)K + ((c1c ^ (c1j & 7)) * 8);
  const bfu* bSrc0 = Bm + (n0 + c0j) * (long)K + ((c0c ^ (c0j & 7)) * 8);
  const bfu* bSrc1 = Bm + (n0 + c1j) * (long)K + ((c1c ^ (c1j & 7)) * 8);

  // stage half-tile `half` (128 rows) of K-tile t into buffer buf
  auto stageA = [&](int t, int buf, int half) {
    long koff = (long)t * 64 + (long)half * 128 * K;
    gload16(aSrc0 + koff, &Asm[buf][half * 8192 + (wave * 64) * 8]);
    gload16(aSrc1 + koff, &Asm[buf][half * 8192 + (512 + wave * 64) * 8]);
  };
  auto stageB = [&](int t, int buf, int half) {
    long koff = (long)t * 64 + (long)half * 128 * K;
    gload16(bSrc0 + koff, &Bsm[buf][half * 8192 + (wave * 64) * 8]);
    gload16(bSrc1 + koff, &Bsm[buf][half * 8192 + (512 + wave * 64) * 8]);
  };
  // fragment reads (swizzled): ks in {0,1} = K-half of the 64-wide tile.
  auto ldsA = [&](int buf, int mf, int ks) -> short8 {
    int row = (mf >> 2) * 128 + wm * 64 + (mf & 3) * 16 + lr;
    int off = (row * 128 + ks * 64 + kq * 16) ^ ((row & 7) << 4);
    return *(const short8*)((const char*)Asm[buf] + off);
  };
  auto ldsB = [&](int buf, int nf, int ks) -> short8 {
    int row = (nf >> 1) * 128 + wn * 32 + (nf & 1) * 16 + lr;
    int off = (row * 128 + ks * 64 + kq * 16) ^ ((row & 7) << 4);
    return *(const short8*)((const char*)Bsm[buf] + off);
  };

  f32x4 acc[8][4] = {};

  // prologue: stage tile 0, wait, barrier
  stageA(0, 0, 0); stageB(0, 0, 0); stageB(0, 0, 1); stageA(0, 0, 1);
  asm volatile("s_waitcnt vmcnt(0)" ::: "memory");
  __builtin_amdgcn_s_barrier();

  for (int t = 0; t < NT; ++t) {
    const int buf = t & 1;
    // issue ALL of tile t+1's staging up front (full-tile prefetch lead)
    if (t + 1 < NT) {
      stageA(t + 1, buf ^ 1, 0);
      stageB(t + 1, buf ^ 1, 0);
      stageB(t + 1, buf ^ 1, 1);
      stageA(t + 1, buf ^ 1, 1);
    }
    // whole-tile compute, compiler-scheduled (no interior barriers/asm)
    short8 a0[4][2], a1[4][2], b0[2][2], b1[2][2];
#pragma unroll
    for (int mf = 0; mf < 4; ++mf) {
      a0[mf][0] = ldsA(buf, mf, 0);
      a0[mf][1] = ldsA(buf, mf, 1);
    }
#pragma unroll
    for (int nf = 0; nf < 2; ++nf) {
      b0[nf][0] = ldsB(buf, nf, 0);
      b0[nf][1] = ldsB(buf, nf, 1);
      b1[nf][0] = ldsB(buf, 2 + nf, 0);
      b1[nf][1] = ldsB(buf, 2 + nf, 1);
    }
    // Q0: acc[0-3][0-1] += a0 x b0
#pragma unroll
    for (int mf = 0; mf < 4; ++mf)
#pragma unroll
      for (int ks = 0; ks < 2; ++ks)
#pragma unroll
        for (int nf = 0; nf < 2; ++nf)
          acc[mf][nf] = __builtin_amdgcn_mfma_f32_16x16x32_bf16(
              a0[mf][ks], b0[nf][ks], acc[mf][nf], 0, 0, 0);
    // load second A-half while Q0 MFMAs run (compiler interleaves)
#pragma unroll
    for (int mf = 0; mf < 4; ++mf) {
      a1[mf][0] = ldsA(buf, 4 + mf, 0);
      a1[mf][1] = ldsA(buf, 4 + mf, 1);
    }
    // Q1: acc[0-3][2-3] += a0 x b1
#pragma unroll
    for (int mf = 0; mf < 4; ++mf)
#pragma unroll
      for (int ks = 0; ks < 2; ++ks)
#pragma unroll
        for (int nf = 0; nf < 2; ++nf)
          acc[mf][2 + nf] = __builtin_amdgcn_mfma_f32_16x16x32_bf16(
              a0[mf][ks], b1[nf][ks], acc[mf][2 + nf], 0, 0, 0);
    // Q2: acc[4-7][2-3] += a1 x b1
#pragma unroll
    for (int mf = 0; mf < 4; ++mf)
#pragma unroll
      for (int ks = 0; ks < 2; ++ks)
#pragma unroll
        for (int nf = 0; nf < 2; ++nf)
          acc[4 + mf][2 + nf] = __builtin_amdgcn_mfma_f32_16x16x32_bf16(
              a1[mf][ks], b1[nf][ks], acc[4 + mf][2 + nf], 0, 0, 0);
    // Q3: acc[4-7][0-1] += a1 x b0 (b0 kept live -- no re-read)
#pragma unroll
    for (int mf = 0; mf < 4; ++mf)
#pragma unroll
      for (int ks = 0; ks < 2; ++ks)
#pragma unroll
        for (int nf = 0; nf < 2; ++nf)
          acc[4 + mf][nf] = __builtin_amdgcn_mfma_f32_16x16x32_bf16(
              a1[mf][ks], b0[nf][ks], acc[4 + mf][nf], 0, 0, 0);
    // tile boundary: t+1's loads (issued a full tile ago) land; all waves
    // done reading buf before t+2 staging overwrites it.
    asm volatile("s_waitcnt vmcnt(0)" ::: "memory");
    __builtin_amdgcn_s_barrier();
  }

  // epilogue: C/D layout col=lane&15, row=(lane>>4)*4+reg; fragment->global
  // mapping mirrors ldsA/ldsB row formulas (half-straddling wave grid).
#pragma unroll
  for (int mf = 0; mf < 8; ++mf)
#pragma unroll
    for (int nf = 0; nf < 4; ++nf)
#pragma unroll
      for (int r = 0; r < 4; ++r) {
        long row = m0 + (mf >> 2) * 128 + wm * 64 + (mf & 3) * 16 + kq * 4 + r;
        long col = n0 + (nf >> 1) * 128 + wn * 32 + (nf & 1) * 16 + lr;
        float v = acc[mf][nf][r];
        if (WRITE_BF16)
          ((bfu*)Cout)[row * N + col] = f2b(v);
        else
          ((float*)Cout)[row * N + col] = v;
      }
}

// ---------------- GEMM: 128^2 m97-style (kept for M=1152 K/V projections) -----
template <int WRITE_BF16>
__global__ __launch_bounds__(256, 2)
void gemm_bt(const bfu* __restrict__ A, const bfu* __restrict__ Bm,
             void* __restrict__ Cout, int M, int N, int K) {
  __shared__ __align__(16) bfu As[128 * 32];
  __shared__ __align__(16) bfu Bs[128 * 32];
  const int tid = threadIdx.x;
  const int wave = tid >> 6, lane = tid & 63;
  const int lr = lane & 15, kq = lane >> 4;
  const int wm = wave >> 1, wn = wave & 1;
  const long m0 = (long)blockIdx.y * 128, n0 = (long)blockIdx.x * 128;

  f32x4 acc[4][4] = {};

  for (int kk = 0; kk < K; kk += 32) {
#pragma unroll
    for (int i = 0; i < 2; ++i) {
      int tt = i * 256 + tid;
      long row = tt >> 2;          // [0,128)
      int col = (tt & 3) * 8;      // {0,8,16,24}
      gload16(A + (m0 + row) * K + kk + col, &As[(i * 256 + wave * 64) * 8]);
      gload16(Bm + (n0 + row) * K + kk + col, &Bs[(i * 256 + wave * 64) * 8]);
    }
    __syncthreads();
    short8 a[4], b[4];
#pragma unroll
    for (int mt = 0; mt < 4; ++mt)
      a[mt] = *(const short8*)&As[(wm * 64 + mt * 16 + lr) * 32 + kq * 8];
#pragma unroll
    for (int nt = 0; nt < 4; ++nt)
      b[nt] = *(const short8*)&Bs[(wn * 64 + nt * 16 + lr) * 32 + kq * 8];
#pragma unroll
    for (int mt = 0; mt < 4; ++mt)
#pragma unroll
      for (int nt = 0; nt < 4; ++nt)
        acc[mt][nt] = __builtin_amdgcn_mfma_f32_16x16x32_bf16(
            a[mt], b[nt], acc[mt][nt], 0, 0, 0);
    __syncthreads();
  }
#pragma unroll
  for (int mt = 0; mt < 4; ++mt)
#pragma unroll
    for (int nt = 0; nt < 4; ++nt)
#pragma unroll
      for (int r = 0; r < 4; ++r) {
        long row = m0 + wm * 64 + mt * 16 + kq * 4 + r;
        long col = n0 + wn * 64 + nt * 16 + lr;
        float v = acc[mt][nt][r];
        if (WRITE_BF16)
          ((bfu*)Cout)[row * N + col] = f2b(v);
        else
          ((float*)Cout)[row * N + col] = v;
      }
}

// ---------------- V transpose: Vb[B*NQ][HID] -> Vt[B*H][HD][NQ] ----------------
__global__ void transpose_v(const bfu* __restrict__ Vb, bfu* __restrict__ Vt) {
  __shared__ bfu t[32][33];
  const int bh = blockIdx.z;            // b*H + h
  const int tq = blockIdx.x;            // nq tile [0,18)
  const int td = blockIdx.y;            // d tile  [0,4)
  const int b = bh >> 5, h = bh & 31;
  const int tx = threadIdx.x & 31, ty = threadIdx.x >> 5;  // ty in [0,8)
  const bfu* src = Vb + ((long)(b * NQn + tq * 32)) * HIDn + h * HDn + td * 32;
#pragma unroll
  for (int i = 0; i < 32; i += 8) t[ty + i][tx] = src[(long)(ty + i) * HIDn + tx];
  __syncthreads();
  bfu* dst = Vt + ((long)bh * HDn + td * 32) * NQn + tq * 32;
#pragma unroll
  for (int i = 0; i < 32; i += 8) dst[(long)(ty + i) * NQn + tx] = t[tx][ty + i];
}

// ---------------- fused attention (R4: K/V LDS-staged, double-buffered) --------
__global__ __launch_bounds__(512, 2)
void attn_kernel(const bfu* __restrict__ Qb, const bfu* __restrict__ Kb,
                 const bfu* __restrict__ Vt, const float* __restrict__ mask,
                 bfu* __restrict__ AO) {
  __shared__ bfu P[64 * 576];      // 73728 B
  __shared__ bfu KV[2][8192];      // 2 x 16KB staging (K tiles, then V tiles)
  __shared__ float red[4][64];     // per-wk partial row sums
  const int swz = blockIdx.x;      // natural order (R2: no XCD chunking!)
  const int h = swz & (Hn - 1);
  const int b = (swz >> 5) & (Bn - 1);
  const int qt0 = swz >> 6;        // [0,64)
  const long q0 = (long)qt0 * 64;
  const int tid = threadIdx.x;
  const int wave = tid >> 6, lane = tid & 63;
  const int lr = lane & 15, kq = lane >> 4;
  const int wk = wave & 3, wq = wave >> 2;
  const float scale = 0.08838834764831845f;  // 1/sqrt(128)

  const bfu* Qbase = Qb + ((long)b * Sn + q0 + wq * 32) * HIDn + h * HDn;
  const bfu* Kblk = Kb + (long)b * NQn * HIDn + h * HDn;
  const bfu* Vblk = Vt + ((long)(b * Hn + h)) * HDn * NQn;
  const float* mbase = mask + ((long)b * Sn + q0 + wq * 32) * NQn + wk * 144;
  char* Pb = (char*)P;

  auto stageK = [&](int mt, int buf) {
#pragma unroll
    for (int i = 0; i < 2; ++i) {
      int c = i * 512 + wave * 64 + lane;
      int j = c >> 4, c16 = c & 15;
      int grow = (j >> 4) * 144 + mt * 16 + (j & 15);
      gload16(Kblk + (long)grow * HIDn + ((c16 ^ (j & 7)) * 8),
              &KV[buf][(i * 512 + wave * 64) * 8]);
    }
  };
  auto stageV = [&](int kt, int buf) {
#pragma unroll
    for (int i = 0; i < 2; ++i) {
      int c = i * 512 + wave * 64 + lane;
      int j = c >> 3, c8 = c & 7;
      gload16(Vblk + (long)j * NQn + kt * 64 + ((c8 ^ (j & 7)) * 8),
              &KV[buf][(i * 512 + wave * 64) * 8]);
    }
  };

  stageK(0, 0);

  short8 qf[2][4];
#pragma unroll
  for (int qt2 = 0; qt2 < 2; ++qt2)
#pragma unroll
    for (int ks = 0; ks < 4; ++ks)
      qf[qt2][ks] =
          *(const short8*)&Qbase[((long)qt2 * 16 + lr) * HIDn + ks * 32 + kq * 8];
  float4 mv[2];
#pragma unroll
  for (int qt2 = 0; qt2 < 2; ++qt2)
    mv[qt2] = *(const float4*)&mbase[((long)qt2 * 16 + lr) * NQn + kq * 4];

  float rsum[2] = {0.f, 0.f};
  for (int mt = 0; mt < 9; ++mt) {
    __syncthreads();  // K(mt) staged + buffers free
    if (mt < 8) stageK(mt + 1, (mt + 1) & 1);
    const int mtn = (mt < 8) ? mt + 1 : mt;
    float4 mvn[2];
#pragma unroll
    for (int qt2 = 0; qt2 < 2; ++qt2)
      mvn[qt2] =
          *(const float4*)&mbase[((long)qt2 * 16 + lr) * NQn + mtn * 16 + kq * 4];

    const char* kb = (const char*)KV[mt & 1];
#pragma unroll
    for (int qt2 = 0; qt2 < 2; ++qt2) {
      const int row = wq * 32 + qt2 * 16 + lr;
      f32x4 sc = {};
#pragma unroll
      for (int ks = 0; ks < 4; ++ks) {
        short8 kf = *(const short8*)(kb + (((wk * 16 + lr) * 256 + ks * 64 + kq * 16) ^
                                           ((lr & 7) << 4)));
        sc = __builtin_amdgcn_mfma_f32_16x16x32_bf16(kf, qf[qt2][ks], sc, 0, 0, 0);
      }
      float p0 = __expf(sc[0] * scale + mv[qt2].x);
      float p1 = __expf(sc[1] * scale + mv[qt2].y);
      float p2 = __expf(sc[2] * scale + mv[qt2].z);
      float p3 = __expf(sc[3] * scale + mv[qt2].w);
      rsum[qt2] += (p0 + p1) + (p2 + p3);
      uint64_t pk = (uint64_t)f2b(p0) | ((uint64_t)f2b(p1) << 16) |
                    ((uint64_t)f2b(p2) << 32) | ((uint64_t)f2b(p3) << 48);
      int off = (row * 1152 + (wk * 288 + mt * 32 + kq * 8)) ^ ((row & 7) << 4);
      *(uint64_t*)(Pb + off) = pk;
    }
    mv[0] = mvn[0];
    mv[1] = mvn[1];
  }
#pragma unroll
  for (int qt2 = 0; qt2 < 2; ++qt2) {
    rsum[qt2] += __shfl_xor(rsum[qt2], 16, 64);
    rsum[qt2] += __shfl_xor(rsum[qt2], 32, 64);
    if (kq == 0) red[wk][wq * 32 + qt2 * 16 + lr] = rsum[qt2];
  }
  __syncthreads();  // P + red complete; KV buffers free

  float inv[2];
#pragma unroll
  for (int qt = 0; qt < 2; ++qt) {
    int row = wq * 32 + qt * 16 + lr;
    inv[qt] = 1.0f / ((red[0][row] + red[1][row]) + (red[2][row] + red[3][row]));
  }

  const int wd = wk;
  stageV(0, 0);
  f32x4 o[2][2] = {};
  for (int kt = 0; kt < 9; ++kt) {
    __syncthreads();  // V(kt) staged
    if (kt < 8) stageV(kt + 1, (kt + 1) & 1);
    const char* vb = (const char*)KV[kt & 1];
#pragma unroll
    for (int sub = 0; sub < 2; ++sub) {
      const int ks = kt * 2 + sub;
      short8 vf[2], pf[2];
#pragma unroll
      for (int dt = 0; dt < 2; ++dt)
        vf[dt] = *(const short8*)(vb + (((wd * 32 + dt * 16 + lr) * 128 + sub * 64 +
                                         kq * 16) ^
                                        ((lr & 7) << 4)));
#pragma unroll
      for (int qt = 0; qt < 2; ++qt) {
        int row = wq * 32 + qt * 16 + lr;
        int off = (row * 1152 + (ks * 64 + kq * 16)) ^ ((row & 7) << 4);
        pf[qt] = *(const short8*)(Pb + off);
      }
#pragma unroll
      for (int qt = 0; qt < 2; ++qt)
#pragma unroll
        for (int dt = 0; dt < 2; ++dt)
          o[qt][dt] = __builtin_amdgcn_mfma_f32_16x16x32_bf16(vf[dt], pf[qt],
                                                              o[qt][dt], 0, 0, 0);
    }
  }
#pragma unroll
  for (int qt = 0; qt < 2; ++qt) {
    const long qrow = (long)b * Sn + q0 + wq * 32 + qt * 16 + lr;
    const float iv = inv[qt];
#pragma unroll
    for (int dt = 0; dt < 2; ++dt) {
      uint64_t pk = (uint64_t)f2b(o[qt][dt][0] * iv) |
                    ((uint64_t)f2b(o[qt][dt][1] * iv) << 16) |
                    ((uint64_t)f2b(o[qt][dt][2] * iv) << 32) |
                    ((uint64_t)f2b(o[qt][dt][3] * iv) << 48);
      *(uint64_t*)&AO[qrow * HIDn + h * HDn + wd * 32 + dt * 16 + kq * 4] = pk;
    }
  }
}

// ------------------------------- launcher --------------------------------------
extern "C" void kernel_launch(void* const* d_in, const int* in_sizes, int n_in,
                              void* d_out, int out_size, void* d_ws, size_t ws_size,
                              hipStream_t stream) {
  const float* hs = (const float*)d_in[0];
  const float* bp = (const float*)d_in[1];
  const float* mask = (const float*)d_in[2];
  const float* Wq = (const float*)d_in[3];
  const float* Wk = (const float*)d_in[4];
  const float* Wv = (const float*)d_in[5];
  const float* Wo = (const float*)d_in[6];
  float* out = (float*)d_out;

  const long M1 = (long)Bn * Sn;   // 8192
  const long M2 = (long)Bn * NQn;  // 1152
  char* ws = (char*)d_ws;
  bfu* hb = (bfu*)(ws + 0);                  // 67,108,864  (also AO)
  bfu* bb = (bfu*)(ws + 67108864);           //  9,437,184
  bfu* w1 = (bfu*)(ws + 76546048);           // 33,554,432  (Wq, later Wo)
  bfu* wkb = (bfu*)(ws + 110100480);         // 33,554,432
  bfu* wvb = (bfu*)(ws + 143654912);         // 33,554,432
  bfu* Qb = (bfu*)(ws + 177209344);          // 67,108,864
  bfu* Kb = (bfu*)(ws + 244318208);          //  9,437,184
  bfu* Vb = (bfu*)(ws + 253755392);          //  9,437,184
  bfu* Vt = (bfu*)(ws + 263192576);          //  9,437,184  -> total 272,629,760

  auto cast = [&](const float* src, bfu* dst, long n) {
    int n8 = (int)(n / 8);
    cast_f32_bf16<<<dim3((n8 + 255) / 256), dim3(256), 0, stream>>>(src, dst, n8);
  };
  cast(hs, hb, M1 * HIDn);
  cast(bp, bb, M2 * HIDn);
  cast(Wq, w1, (long)HIDn * HIDn);
  cast(Wk, wkb, (long)HIDn * HIDn);
  cast(Wv, wvb, (long)HIDn * HIDn);

  gemm_bt256<1><<<dim3(HIDn / 256, M1 / 256), dim3(512), 0, stream>>>(
      hb, w1, Qb, (int)M1, HIDn, HIDn);
  gemm_bt<1><<<dim3(HIDn / 128, M2 / 128), dim3(256), 0, stream>>>(
      bb, wkb, Kb, (int)M2, HIDn, HIDn);
  gemm_bt<1><<<dim3(HIDn / 128, M2 / 128), dim3(256), 0, stream>>>(
      bb, wvb, Vb, (int)M2, HIDn, HIDn);

  cast(Wo, w1, (long)HIDn * HIDn);  // w1 slot free after Q-proj
  transpose_v<<<dim3(NQn / 32, HDn / 32, Bn * Hn), dim3(256), 0, stream>>>(Vb, Vt);

  attn_kernel<<<dim3((Sn / 64) * Bn * Hn), dim3(512), 0, stream>>>(
      Qb, Kb, Vt, mask, hb /*AO aliases hb*/);

  gemm_bt256<0><<<dim3(HIDn / 256, M1 / 256), dim3(512), 0, stream>>>(
      hb, w1, out, (int)M1, HIDn, HIDn);
}

// Round 9
// 986.251 us; speedup vs baseline: 1.4409x; 1.1148x over previous
//
#include <hip/hip_runtime.h>
#include <stdint.h>

// Problem constants
#define Bn   2
#define Sn   4096
#define NQn  576
#define Hn   32
#define HDn  128
#define HIDn 4096

typedef unsigned short bfu;  // raw bf16 bits
typedef short short8 __attribute__((ext_vector_type(8)));
typedef float f32x4 __attribute__((ext_vector_type(4)));

__device__ __forceinline__ bfu f2b(float f) {
  uint32_t x = __builtin_bit_cast(uint32_t, f);
  return (bfu)((x + 0x7fffu + ((x >> 16) & 1u)) >> 16);  // RNE
}

__device__ __forceinline__ void gload16(const void* g, void* l) {
  // async global->LDS, 16B per lane; LDS dest = wave-uniform base + lane*16
  __builtin_amdgcn_global_load_lds(
      (const __attribute__((address_space(1))) uint32_t*)g,
      (__attribute__((address_space(3))) uint32_t*)l, 16, 0, 0);
}

// ---------------- cast f32 -> bf16 (vectorized: 2x float4 in, 16B out) ---------
__global__ void cast_f32_bf16(const float* __restrict__ in, bfu* __restrict__ out,
                              int n8) {
  int i = blockIdx.x * 256 + threadIdx.x;
  if (i >= n8) return;
  const float4* in4 = (const float4*)in;
  float4 a = in4[2 * i], c = in4[2 * i + 1];
  short8 v;
  v[0] = (short)f2b(a.x); v[1] = (short)f2b(a.y);
  v[2] = (short)f2b(a.z); v[3] = (short)f2b(a.w);
  v[4] = (short)f2b(c.x); v[5] = (short)f2b(c.y);
  v[6] = (short)f2b(c.z); v[7] = (short)f2b(c.w);
  ((short8*)out)[i] = v;
}

// ======== 256^2 whole-tile-pipelined GEMM (R8-verified): C = A @ Bm^T =========
template <int WRITE_BF16>
__global__ __launch_bounds__(512, 2)
void gemm_bt256(const bfu* __restrict__ A, const bfu* __restrict__ Bm,
                void* __restrict__ Cout, int M, int N, int K) {
  __shared__ __align__(16) bfu Asm[2][256 * 64];  // 32KB per buffer
  __shared__ __align__(16) bfu Bsm[2][256 * 64];
  const int tid = threadIdx.x;
  const int wave = tid >> 6, lane = tid & 63;
  const int lr = lane & 15, kq = lane >> 4;
  const int wm = wave >> 2, wn = wave & 3;  // 2 x 4 wave grid
  const long m0 = (long)blockIdx.y * 256, n0 = (long)blockIdx.x * 256;
  const int NT = K >> 6;  // K-tiles of 64

  const int c0j = tid >> 3, c0c = tid & 7;
  const int c1j = (512 + tid) >> 3, c1c = tid & 7;
  const bfu* aSrc0 = A + (m0 + c0j) * (long)K + ((c0c ^ (c0j & 7)) * 8);
  const bfu* aSrc1 = A + (m0 + c1j) * (long)K + ((c1c ^ (c1j & 7)) * 8);
  const bfu* bSrc0 = Bm + (n0 + c0j) * (long)K + ((c0c ^ (c0j & 7)) * 8);
  const bfu* bSrc1 = Bm + (n0 + c1j) * (long)K + ((c1c ^ (c1j & 7)) * 8);

  auto stageA = [&](int t, int buf, int half) {
    long koff = (long)t * 64 + (long)half * 128 * K;
    gload16(aSrc0 + koff, &Asm[buf][half * 8192 + (wave * 64) * 8]);
    gload16(aSrc1 + koff, &Asm[buf][half * 8192 + (512 + wave * 64) * 8]);
  };
  auto stageB = [&](int t, int buf, int half) {
    long koff = (long)t * 64 + (long)half * 128 * K;
    gload16(bSrc0 + koff, &Bsm[buf][half * 8192 + (wave * 64) * 8]);
    gload16(bSrc1 + koff, &Bsm[buf][half * 8192 + (512 + wave * 64) * 8]);
  };
  auto ldsA = [&](int buf, int mf, int ks) -> short8 {
    int row = (mf >> 2) * 128 + wm * 64 + (mf & 3) * 16 + lr;
    int off = (row * 128 + ks * 64 + kq * 16) ^ ((row & 7) << 4);
    return *(const short8*)((const char*)Asm[buf] + off);
  };
  auto ldsB = [&](int buf, int nf, int ks) -> short8 {
    int row = (nf >> 1) * 128 + wn * 32 + (nf & 1) * 16 + lr;
    int off = (row * 128 + ks * 64 + kq * 16) ^ ((row & 7) << 4);
    return *(const short8*)((const char*)Bsm[buf] + off);
  };

  f32x4 acc[8][4] = {};

  stageA(0, 0, 0); stageB(0, 0, 0); stageB(0, 0, 1); stageA(0, 0, 1);
  asm volatile("s_waitcnt vmcnt(0)" ::: "memory");
  __builtin_amdgcn_s_barrier();

  for (int t = 0; t < NT; ++t) {
    const int buf = t & 1;
    if (t + 1 < NT) {
      stageA(t + 1, buf ^ 1, 0);
      stageB(t + 1, buf ^ 1, 0);
      stageB(t + 1, buf ^ 1, 1);
      stageA(t + 1, buf ^ 1, 1);
    }
    short8 a0[4][2], a1[4][2], b0[2][2], b1[2][2];
#pragma unroll
    for (int mf = 0; mf < 4; ++mf) {
      a0[mf][0] = ldsA(buf, mf, 0);
      a0[mf][1] = ldsA(buf, mf, 1);
    }
#pragma unroll
    for (int nf = 0; nf < 2; ++nf) {
      b0[nf][0] = ldsB(buf, nf, 0);
      b0[nf][1] = ldsB(buf, nf, 1);
      b1[nf][0] = ldsB(buf, 2 + nf, 0);
      b1[nf][1] = ldsB(buf, 2 + nf, 1);
    }
#pragma unroll
    for (int mf = 0; mf < 4; ++mf)
#pragma unroll
      for (int ks = 0; ks < 2; ++ks)
#pragma unroll
        for (int nf = 0; nf < 2; ++nf)
          acc[mf][nf] = __builtin_amdgcn_mfma_f32_16x16x32_bf16(
              a0[mf][ks], b0[nf][ks], acc[mf][nf], 0, 0, 0);
#pragma unroll
    for (int mf = 0; mf < 4; ++mf) {
      a1[mf][0] = ldsA(buf, 4 + mf, 0);
      a1[mf][1] = ldsA(buf, 4 + mf, 1);
    }
#pragma unroll
    for (int mf = 0; mf < 4; ++mf)
#pragma unroll
      for (int ks = 0; ks < 2; ++ks)
#pragma unroll
        for (int nf = 0; nf < 2; ++nf)
          acc[mf][2 + nf] = __builtin_amdgcn_mfma_f32_16x16x32_bf16(
              a0[mf][ks], b1[nf][ks], acc[mf][2 + nf], 0, 0, 0);
#pragma unroll
    for (int mf = 0; mf < 4; ++mf)
#pragma unroll
      for (int ks = 0; ks < 2; ++ks)
#pragma unroll
        for (int nf = 0; nf < 2; ++nf)
          acc[4 + mf][2 + nf] = __builtin_amdgcn_mfma_f32_16x16x32_bf16(
              a1[mf][ks], b1[nf][ks], acc[4 + mf][2 + nf], 0, 0, 0);
#pragma unroll
    for (int mf = 0; mf < 4; ++mf)
#pragma unroll
      for (int ks = 0; ks < 2; ++ks)
#pragma unroll
        for (int nf = 0; nf < 2; ++nf)
          acc[4 + mf][nf] = __builtin_amdgcn_mfma_f32_16x16x32_bf16(
              a1[mf][ks], b0[nf][ks], acc[4 + mf][nf], 0, 0, 0);
    asm volatile("s_waitcnt vmcnt(0)" ::: "memory");
    __builtin_amdgcn_s_barrier();
  }

#pragma unroll
  for (int mf = 0; mf < 8; ++mf)
#pragma unroll
    for (int nf = 0; nf < 4; ++nf)
#pragma unroll
      for (int r = 0; r < 4; ++r) {
        long row = m0 + (mf >> 2) * 128 + wm * 64 + (mf & 3) * 16 + kq * 4 + r;
        long col = n0 + (nf >> 1) * 128 + wn * 32 + (nf & 1) * 16 + lr;
        float v = acc[mf][nf][r];
        if (WRITE_BF16)
          ((bfu*)Cout)[row * N + col] = f2b(v);
        else
          ((float*)Cout)[row * N + col] = v;
      }
}

// ---------------- GEMM: 128^2 m97-style (kept for M=1152 K/V projections) -----
template <int WRITE_BF16>
__global__ __launch_bounds__(256, 2)
void gemm_bt(const bfu* __restrict__ A, const bfu* __restrict__ Bm,
             void* __restrict__ Cout, int M, int N, int K) {
  __shared__ __align__(16) bfu As[128 * 32];
  __shared__ __align__(16) bfu Bs[128 * 32];
  const int tid = threadIdx.x;
  const int wave = tid >> 6, lane = tid & 63;
  const int lr = lane & 15, kq = lane >> 4;
  const int wm = wave >> 1, wn = wave & 1;
  const long m0 = (long)blockIdx.y * 128, n0 = (long)blockIdx.x * 128;

  f32x4 acc[4][4] = {};

  for (int kk = 0; kk < K; kk += 32) {
#pragma unroll
    for (int i = 0; i < 2; ++i) {
      int tt = i * 256 + tid;
      long row = tt >> 2;
      int col = (tt & 3) * 8;
      gload16(A + (m0 + row) * K + kk + col, &As[(i * 256 + wave * 64) * 8]);
      gload16(Bm + (n0 + row) * K + kk + col, &Bs[(i * 256 + wave * 64) * 8]);
    }
    __syncthreads();
    short8 a[4], b[4];
#pragma unroll
    for (int mt = 0; mt < 4; ++mt)
      a[mt] = *(const short8*)&As[(wm * 64 + mt * 16 + lr) * 32 + kq * 8];
#pragma unroll
    for (int nt = 0; nt < 4; ++nt)
      b[nt] = *(const short8*)&Bs[(wn * 64 + nt * 16 + lr) * 32 + kq * 8];
#pragma unroll
    for (int mt = 0; mt < 4; ++mt)
#pragma unroll
      for (int nt = 0; nt < 4; ++nt)
        acc[mt][nt] = __builtin_amdgcn_mfma_f32_16x16x32_bf16(
            a[mt], b[nt], acc[mt][nt], 0, 0, 0);
    __syncthreads();
  }
#pragma unroll
  for (int mt = 0; mt < 4; ++mt)
#pragma unroll
    for (int nt = 0; nt < 4; ++nt)
#pragma unroll
      for (int r = 0; r < 4; ++r) {
        long row = m0 + wm * 64 + mt * 16 + kq * 4 + r;
        long col = n0 + wn * 64 + nt * 16 + lr;
        float v = acc[mt][nt][r];
        if (WRITE_BF16)
          ((bfu*)Cout)[row * N + col] = f2b(v);
        else
          ((float*)Cout)[row * N + col] = v;
      }
}

// ---------------- V transpose: Vb[B*NQ][HID] -> Vt[B*H][HD][NQ] ----------------
__global__ void transpose_v(const bfu* __restrict__ Vb, bfu* __restrict__ Vt) {
  __shared__ bfu t[32][33];
  const int bh = blockIdx.z;
  const int tq = blockIdx.x;
  const int td = blockIdx.y;
  const int b = bh >> 5, h = bh & 31;
  const int tx = threadIdx.x & 31, ty = threadIdx.x >> 5;
  const bfu* src = Vb + ((long)(b * NQn + tq * 32)) * HIDn + h * HDn + td * 32;
#pragma unroll
  for (int i = 0; i < 32; i += 8) t[ty + i][tx] = src[(long)(ty + i) * HIDn + tx];
  __syncthreads();
  bfu* dst = Vt + ((long)bh * HDn + td * 32) * NQn + tq * 32;
#pragma unroll
  for (int i = 0; i < 32; i += 8) dst[(long)(ty + i) * NQn + tx] = t[tx][ty + i];
}

// ========== fused attention R9: flash-style, NO P-in-LDS ======================
// R8 post-mortem: 45k cyc/block wall vs ~10k pipe work; 1 block/CU (107.5KB
// LDS, P=73.7KB) + 18 barrier-locked rounds + P LDS round-trip. R9: block =
// 256 thr = 4 waves; wave w owns 16 q-rows and iterates ALL 576 keys in 18
// 32-key steps, fully fused: QK^T (swapped: mfma(K,Q) -> lane holds
// S^T[key=kq*4+r][q=lr]) -> mask+exp+pack bf16 -> IN-WAVE EXCHANGE to build
// the PV B-operand (P^T frag: lane needs keys kq*8+e at q=lr):
//   b[j] = select(kq<2, shfl(pk_mt0[j&1], src), shfl(pk_mt1[j&1], src)),
//   src = lr + 16*((kq&1)*2 + (j>>1))        [derived + spot-verified]
// -> 8 PV MFMAs (d-tiles) accumulating unnormalized; normalize in epilogue
// (rsum lane-local + 2 shfl_xor). K/V staged in LDS dbuf (32KB total ->
// 3 blocks/CU, 12 waves/CU). K tile [32][128d] XOR-swizzled (256B rows,
// rule #21 both-sides); V tile [128d][32] linear (64B rows: 8 distinct
// 16B slots/wave = minimum phases, no swizzle needed). Natural block order
// (R2: no XCD chunking). No max-subtract (scores bounded ~|10|, f32 exp).
__global__ __launch_bounds__(256, 3)
void attn_kernel(const bfu* __restrict__ Qb, const bfu* __restrict__ Kb,
                 const bfu* __restrict__ Vt, const float* __restrict__ mask,
                 bfu* __restrict__ AO) {
  __shared__ __align__(16) bfu Ks[2][4096];  // 2 x 8KB: [32 keys][128 d] swz
  __shared__ __align__(16) bfu Vs[2][4096];  // 2 x 8KB: [128 d][32 keys] lin
  const int bid = blockIdx.x;                // natural order
  const int h = bid & (Hn - 1);
  const int b = (bid >> 5) & (Bn - 1);
  const int qt0 = bid >> 6;                  // [0,64)
  const long q0 = (long)qt0 * 64;
  const int tid = threadIdx.x;
  const int wave = tid >> 6, lane = tid & 63;
  const int lr = lane & 15, kq = lane >> 4;
  const float scale = 0.08838834764831845f;  // 1/sqrt(128)

  const long qrow = (long)b * Sn + q0 + wave * 16 + lr;  // this lane's q row
  const bfu* Kblk = Kb + (long)b * NQn * HIDn + h * HDn;
  const bfu* Vblk = Vt + ((long)(b * Hn + h)) * HDn * NQn;
  const float* mrow = mask + ((long)b * Sn + q0 + wave * 16 + lr) * NQn;

  // stage K-step kt (32 keys x 128 d, 8KB): rows j=key, 16 chunks/row,
  // source col chunk = c16 ^ (j&7)  (inverse of read swizzle)
  auto stageK = [&](int kt, int buf) {
#pragma unroll
    for (int i = 0; i < 2; ++i) {
      int c = i * 256 + tid;
      int j = c >> 4, c16 = c & 15;
      gload16(Kblk + (long)(kt * 32 + j) * HIDn + ((c16 ^ (j & 7)) * 8),
              &Ks[buf][(i * 256 + wave * 64) * 8]);
    }
  };
  // stage V-step kt (128 d x 32 keys, 8KB): rows j=d, 4 chunks/row, linear
  auto stageV = [&](int kt, int buf) {
#pragma unroll
    for (int i = 0; i < 2; ++i) {
      int c = i * 256 + tid;
      int j = c >> 2, c4 = c & 3;
      gload16(Vblk + (long)j * NQn + kt * 32 + c4 * 8,
              &Vs[buf][(i * 256 + wave * 64) * 8]);
    }
  };

  stageK(0, 0);
  stageV(0, 0);

  // Q fragments (one-time, from L2): B-frag of mfma(K,Q): lane needs
  // Q[q=lr][d=kq*8+e] for each 32-d slice ks
  const bfu* Qbase = Qb + qrow * HIDn + h * HDn;
  short8 qf[4];
#pragma unroll
  for (int ks = 0; ks < 4; ++ks)
    qf[ks] = *(const short8*)&Qbase[ks * 32 + kq * 8];

  f32x4 o[8] = {};  // PV acc: o[dt], C: col=lr=q, row=kq*4+r = d in dt tile
  float rsum = 0.f;

  for (int kt = 0; kt < 18; ++kt) {
    __syncthreads();  // K/V(kt) landed (vmcnt drained) + prev buf reads done
    const int buf = kt & 1;
    if (kt < 17) {
      stageK(kt + 1, buf ^ 1);
      stageV(kt + 1, buf ^ 1);
    }
    // ---- QK^T: two 16-key tiles ----
    const char* kb = (const char*)Ks[buf];
    f32x4 s0 = {}, s1 = {};
#pragma unroll
    for (int ks = 0; ks < 4; ++ks) {
      short8 kf0 = *(const short8*)(kb + ((lr * 256 + ks * 64 + kq * 16) ^
                                          ((lr & 7) << 4)));
      short8 kf1 = *(const short8*)(kb + (((16 + lr) * 256 + ks * 64 + kq * 16) ^
                                          ((lr & 7) << 4)));
      s0 = __builtin_amdgcn_mfma_f32_16x16x32_bf16(kf0, qf[ks], s0, 0, 0, 0);
      s1 = __builtin_amdgcn_mfma_f32_16x16x32_bf16(kf1, qf[ks], s1, 0, 0, 0);
    }
    // ---- mask + exp + pack (keys kt*32 + kq*4 + r | +16) ----
    float4 m0 = *(const float4*)&mrow[kt * 32 + kq * 4];
    float4 m1 = *(const float4*)&mrow[kt * 32 + 16 + kq * 4];
    float p00 = __expf(s0[0] * scale + m0.x), p01 = __expf(s0[1] * scale + m0.y);
    float p02 = __expf(s0[2] * scale + m0.z), p03 = __expf(s0[3] * scale + m0.w);
    float p10 = __expf(s1[0] * scale + m1.x), p11 = __expf(s1[1] * scale + m1.y);
    float p12 = __expf(s1[2] * scale + m1.z), p13 = __expf(s1[3] * scale + m1.w);
    rsum += ((p00 + p01) + (p02 + p03)) + ((p10 + p11) + (p12 + p13));
    int pk0_0 = (int)((uint32_t)f2b(p00) | ((uint32_t)f2b(p01) << 16));
    int pk0_1 = (int)((uint32_t)f2b(p02) | ((uint32_t)f2b(p03) << 16));
    int pk1_0 = (int)((uint32_t)f2b(p10) | ((uint32_t)f2b(p11) << 16));
    int pk1_1 = (int)((uint32_t)f2b(p12) | ((uint32_t)f2b(p13) << 16));
    // ---- exchange: build P^T B-frag (lane: keys kq*8+e, q=lr) ----
    const int sLo = lr + (((kq & 1) << 1) << 4);       // kq_src=(kq&1)*2
    const int sHi = sLo + 16;                          // kq_src=(kq&1)*2+1
    int b0, b1, b2, b3;
    {
      int v0 = __shfl(pk0_0, sLo, 64), v1 = __shfl(pk1_0, sLo, 64);
      b0 = (kq < 2) ? v0 : v1;
      v0 = __shfl(pk0_1, sLo, 64); v1 = __shfl(pk1_1, sLo, 64);
      b1 = (kq < 2) ? v0 : v1;
      v0 = __shfl(pk0_0, sHi, 64); v1 = __shfl(pk1_0, sHi, 64);
      b2 = (kq < 2) ? v0 : v1;
      v0 = __shfl(pk0_1, sHi, 64); v1 = __shfl(pk1_1, sHi, 64);
      b3 = (kq < 2) ? v0 : v1;
    }
    int4 pfi = {b0, b1, b2, b3};
    short8 pfrag = __builtin_bit_cast(short8, pfi);
    // ---- PV: 8 d-tiles, A=V^T frag (row=d=dt*16+lr, k=keys kq*8+e) ----
    const char* vb = (const char*)Vs[buf];
#pragma unroll
    for (int dt = 0; dt < 8; ++dt) {
      short8 vf = *(const short8*)(vb + ((dt * 16 + lr) * 64 + kq * 16));
      o[dt] = __builtin_amdgcn_mfma_f32_16x16x32_bf16(vf, pfrag, o[dt], 0, 0, 0);
    }
  }

  // row sum over kq groups (keys otherwise lane-local) -> normalize
  rsum += __shfl_xor(rsum, 16, 64);
  rsum += __shfl_xor(rsum, 32, 64);
  const float inv = 1.0f / rsum;

  bfu* Obase = AO + qrow * HIDn + h * HDn;
#pragma unroll
  for (int dt = 0; dt < 8; ++dt) {
    uint64_t pk = (uint64_t)f2b(o[dt][0] * inv) |
                  ((uint64_t)f2b(o[dt][1] * inv) << 16) |
                  ((uint64_t)f2b(o[dt][2] * inv) << 32) |
                  ((uint64_t)f2b(o[dt][3] * inv) << 48);
    *(uint64_t*)&Obase[dt * 16 + kq * 4] = pk;
  }
}

// ------------------------------- launcher --------------------------------------
extern "C" void kernel_launch(void* const* d_in, const int* in_sizes, int n_in,
                              void* d_out, int out_size, void* d_ws, size_t ws_size,
                              hipStream_t stream) {
  const float* hs = (const float*)d_in[0];
  const float* bp = (const float*)d_in[1];
  const float* mask = (const float*)d_in[2];
  const float* Wq = (const float*)d_in[3];
  const float* Wk = (const float*)d_in[4];
  const float* Wv = (const float*)d_in[5];
  const float* Wo = (const float*)d_in[6];
  float* out = (float*)d_out;

  const long M1 = (long)Bn * Sn;   // 8192
  const long M2 = (long)Bn * NQn;  // 1152
  char* ws = (char*)d_ws;
  bfu* hb = (bfu*)(ws + 0);                  // 67,108,864  (also AO)
  bfu* bb = (bfu*)(ws + 67108864);           //  9,437,184
  bfu* w1 = (bfu*)(ws + 76546048);           // 33,554,432  (Wq, later Wo)
  bfu* wkb = (bfu*)(ws + 110100480);         // 33,554,432
  bfu* wvb = (bfu*)(ws + 143654912);         // 33,554,432
  bfu* Qb = (bfu*)(ws + 177209344);          // 67,108,864
  bfu* Kb = (bfu*)(ws + 244318208);          //  9,437,184
  bfu* Vb = (bfu*)(ws + 253755392);          //  9,437,184
  bfu* Vt = (bfu*)(ws + 263192576);          //  9,437,184  -> total 272,629,760

  auto cast = [&](const float* src, bfu* dst, long n) {
    int n8 = (int)(n / 8);
    cast_f32_bf16<<<dim3((n8 + 255) / 256), dim3(256), 0, stream>>>(src, dst, n8);
  };
  cast(hs, hb, M1 * HIDn);
  cast(bp, bb, M2 * HIDn);
  cast(Wq, w1, (long)HIDn * HIDn);
  cast(Wk, wkb, (long)HIDn * HIDn);
  cast(Wv, wvb, (long)HIDn * HIDn);

  gemm_bt256<1><<<dim3(HIDn / 256, M1 / 256), dim3(512), 0, stream>>>(
      hb, w1, Qb, (int)M1, HIDn, HIDn);
  gemm_bt<1><<<dim3(HIDn / 128, M2 / 128), dim3(256), 0, stream>>>(
      bb, wkb, Kb, (int)M2, HIDn, HIDn);
  gemm_bt<1><<<dim3(HIDn / 128, M2 / 128), dim3(256), 0, stream>>>(
      bb, wvb, Vb, (int)M2, HIDn, HIDn);

  cast(Wo, w1, (long)HIDn * HIDn);  // w1 slot free after Q-proj
  transpose_v<<<dim3(NQn / 32, HDn / 32, Bn * Hn), dim3(256), 0, stream>>>(Vb, Vt);

  attn_kernel<<<dim3((Sn / 64) * Bn * Hn), dim3(256), 0, stream>>>(
      Qb, Kb, Vt, mask, hb /*AO aliases hb*/);

  gemm_bt256<0><<<dim3(HIDn / 256, M1 / 256), dim3(512), 0, stream>>>(
      hb, w1, out, (int)M1, HIDn, HIDn);
}

// Round 10
// 951.215 us; speedup vs baseline: 1.4939x; 1.0368x over previous
//
#include <hip/hip_runtime.h>
#include <stdint.h>

// Problem constants
#define Bn   2
#define Sn   4096
#define NQn  576
#define Hn   32
#define HDn  128
#define HIDn 4096

typedef unsigned short bfu;  // raw bf16 bits
typedef short short8 __attribute__((ext_vector_type(8)));
typedef float f32x4 __attribute__((ext_vector_type(4)));
typedef float f32x16 __attribute__((ext_vector_type(16)));

__device__ __forceinline__ bfu f2b(float f) {
  uint32_t x = __builtin_bit_cast(uint32_t, f);
  return (bfu)((x + 0x7fffu + ((x >> 16) & 1u)) >> 16);  // RNE
}

__device__ __forceinline__ void gload16(const void* g, void* l) {
  // async global->LDS, 16B per lane; LDS dest = wave-uniform base + lane*16
  __builtin_amdgcn_global_load_lds(
      (const __attribute__((address_space(1))) uint32_t*)g,
      (__attribute__((address_space(3))) uint32_t*)l, 16, 0, 0);
}

// ---------------- cast f32 -> bf16 (vectorized: 2x float4 in, 16B out) ---------
__global__ void cast_f32_bf16(const float* __restrict__ in, bfu* __restrict__ out,
                              int n8) {
  int i = blockIdx.x * 256 + threadIdx.x;
  if (i >= n8) return;
  const float4* in4 = (const float4*)in;
  float4 a = in4[2 * i], c = in4[2 * i + 1];
  short8 v;
  v[0] = (short)f2b(a.x); v[1] = (short)f2b(a.y);
  v[2] = (short)f2b(a.z); v[3] = (short)f2b(a.w);
  v[4] = (short)f2b(c.x); v[5] = (short)f2b(c.y);
  v[6] = (short)f2b(c.z); v[7] = (short)f2b(c.w);
  ((short8*)out)[i] = v;
}

// ======== 256^2 whole-tile-pipelined GEMM, 32x32x16 MFMA: C = A @ Bm^T ========
// R9: R8 whole-tile structure (passed, 0 conflicts) with the MFMA shape
// switched 16x16x32 -> 32x32x16: same FLOPs in half the instructions, pipe
// rate 2495 vs 2075 TF (m119/m06) -> MFMA cycles/tile 2483->2066. Fragment
// layouts by symmetry with the verified 16x16x32 mapping:
//   A/B operand: row(=n-row for B^T) = lane&31, k = (lane>>5)*8 + e
//   C/D: col = lane&31, row = (reg&3) + 8*(reg>>2) + 4*(lane>>5)  [m74/m101]
// Read pattern under the (row&7)<<4 XOR swizzle: 8-lane service phases hit
// banks c+{0,4,..,28} -> conflict-free (verified arithmetic). Staging and the
// whole-tile double-buffer + single vmcnt(0)+s_barrier per tile: as R8.
template <int WRITE_BF16>
__global__ __launch_bounds__(512, 2)
void gemm_bt256(const bfu* __restrict__ A, const bfu* __restrict__ Bm,
                void* __restrict__ Cout, int M, int N, int K) {
  __shared__ __align__(16) bfu Asm[2][256 * 64];  // 32KB per buffer
  __shared__ __align__(16) bfu Bsm[2][256 * 64];
  const int tid = threadIdx.x;
  const int wave = tid >> 6, lane = tid & 63;
  const int l31 = lane & 31, l5 = lane >> 5;
  const int wm = wave >> 2, wn = wave & 3;  // 2 x 4 wave grid
  const long m0 = (long)blockIdx.y * 256, n0 = (long)blockIdx.x * 256;
  const int NT = K >> 6;  // K-tiles of 64

  // per-thread staging sources. chunk c = rnd*512+tid ; row j=c>>3 (0..127),
  // chunk-in-row c8=c&7 ; global col chunk = c8 ^ (j&7) (inverse of read swz).
  const int c0j = tid >> 3, c0c = tid & 7;
  const int c1j = (512 + tid) >> 3, c1c = tid & 7;  // (512+tid)&7 == tid&7
  const bfu* aSrc0 = A + (m0 + c0j) * (long)K + ((c0c ^ (c0j & 7)) * 8);
  const bfu* aSrc1 = A + (m0 + c1j) * (long)K + ((c1c ^ (c1j & 7)) * 8);
  const bfu* bSrc0 = Bm + (n0 + c0j) * (long)K + ((c0c ^ (c0j & 7)) * 8);
  const bfu* bSrc1 = Bm + (n0 + c1j) * (long)K + ((c1c ^ (c1j & 7)) * 8);

  auto stageA = [&](int t, int buf, int half) {
    long koff = (long)t * 64 + (long)half * 128 * K;
    gload16(aSrc0 + koff, &Asm[buf][half * 8192 + (wave * 64) * 8]);
    gload16(aSrc1 + koff, &Asm[buf][half * 8192 + (512 + wave * 64) * 8]);
  };
  auto stageB = [&](int t, int buf, int half) {
    long koff = (long)t * 64 + (long)half * 128 * K;
    gload16(bSrc0 + koff, &Bsm[buf][half * 8192 + (wave * 64) * 8]);
    gload16(bSrc1 + koff, &Bsm[buf][half * 8192 + (512 + wave * 64) * 8]);
  };
  // fragment reads (swizzled): ks in {0..3} = 16-wide K slice; 16B per lane
  auto ldsA = [&](int buf, int mf, int ks) -> short8 {
    int row = wm * 128 + mf * 32 + l31;
    int off = (row * 128 + ks * 32 + l5 * 16) ^ ((row & 7) << 4);
    return *(const short8*)((const char*)Asm[buf] + off);
  };
  auto ldsB = [&](int buf, int nf, int ks) -> short8 {
    int row = nf * 128 + wn * 32 + l31;
    int off = (row * 128 + ks * 32 + l5 * 16) ^ ((row & 7) << 4);
    return *(const short8*)((const char*)Bsm[buf] + off);
  };

  f32x16 acc[4][2] = {};

  // prologue: stage tile 0, wait, barrier
  stageA(0, 0, 0); stageB(0, 0, 0); stageB(0, 0, 1); stageA(0, 0, 1);
  asm volatile("s_waitcnt vmcnt(0)" ::: "memory");
  __builtin_amdgcn_s_barrier();

  for (int t = 0; t < NT; ++t) {
    const int buf = t & 1;
    if (t + 1 < NT) {
      stageA(t + 1, buf ^ 1, 0);
      stageB(t + 1, buf ^ 1, 0);
      stageB(t + 1, buf ^ 1, 1);
      stageA(t + 1, buf ^ 1, 1);
    }
    short8 b[2][4], a[2][4];
#pragma unroll
    for (int nf = 0; nf < 2; ++nf)
#pragma unroll
      for (int ks = 0; ks < 4; ++ks) b[nf][ks] = ldsB(buf, nf, ks);
#pragma unroll
    for (int mf = 0; mf < 2; ++mf)
#pragma unroll
      for (int ks = 0; ks < 4; ++ks) a[mf][ks] = ldsA(buf, mf, ks);
#pragma unroll
    for (int mf = 0; mf < 2; ++mf)
#pragma unroll
      for (int ks = 0; ks < 4; ++ks)
#pragma unroll
        for (int nf = 0; nf < 2; ++nf)
          acc[mf][nf] = __builtin_amdgcn_mfma_f32_32x32x16_bf16(
              a[mf][ks], b[nf][ks], acc[mf][nf], 0, 0, 0);
#pragma unroll
    for (int mf = 0; mf < 2; ++mf)
#pragma unroll
      for (int ks = 0; ks < 4; ++ks) a[mf][ks] = ldsA(buf, 2 + mf, ks);
#pragma unroll
    for (int mf = 0; mf < 2; ++mf)
#pragma unroll
      for (int ks = 0; ks < 4; ++ks)
#pragma unroll
        for (int nf = 0; nf < 2; ++nf)
          acc[2 + mf][nf] = __builtin_amdgcn_mfma_f32_32x32x16_bf16(
              a[mf][ks], b[nf][ks], acc[2 + mf][nf], 0, 0, 0);
    // tile boundary: t+1's loads (issued a full tile ~4500cy ago) land.
    asm volatile("s_waitcnt vmcnt(0)" ::: "memory");
    __builtin_amdgcn_s_barrier();
  }

  // epilogue: 32x32 C/D layout col=lane&31, row=(reg&3)+8*(reg>>2)+4*(lane>>5)
#pragma unroll
  for (int mf = 0; mf < 4; ++mf)
#pragma unroll
    for (int nf = 0; nf < 2; ++nf)
#pragma unroll
      for (int r = 0; r < 16; ++r) {
        long row = m0 + wm * 128 + mf * 32 + (r & 3) + 8 * (r >> 2) + 4 * l5;
        long col = n0 + nf * 128 + wn * 32 + l31;
        float v = acc[mf][nf][r];
        if (WRITE_BF16)
          ((bfu*)Cout)[row * N + col] = f2b(v);
        else
          ((float*)Cout)[row * N + col] = v;
      }
}

// ---------------- GEMM: 128^2 m97-style (batched K/V projection) --------------
template <int WRITE_BF16>
__global__ __launch_bounds__(256, 2)
void gemm_bt(const bfu* __restrict__ A, const bfu* __restrict__ Bm,
             void* __restrict__ Cout, int M, int N, int K) {
  __shared__ __align__(16) bfu As[128 * 32];
  __shared__ __align__(16) bfu Bs[128 * 32];
  const int tid = threadIdx.x;
  const int wave = tid >> 6, lane = tid & 63;
  const int lr = lane & 15, kq = lane >> 4;
  const int wm = wave >> 1, wn = wave & 1;
  const long m0 = (long)blockIdx.y * 128, n0 = (long)blockIdx.x * 128;

  f32x4 acc[4][4] = {};

  for (int kk = 0; kk < K; kk += 32) {
#pragma unroll
    for (int i = 0; i < 2; ++i) {
      int tt = i * 256 + tid;
      long row = tt >> 2;
      int col = (tt & 3) * 8;
      gload16(A + (m0 + row) * K + kk + col, &As[(i * 256 + wave * 64) * 8]);
      gload16(Bm + (n0 + row) * K + kk + col, &Bs[(i * 256 + wave * 64) * 8]);
    }
    __syncthreads();
    short8 a[4], b[4];
#pragma unroll
    for (int mt = 0; mt < 4; ++mt)
      a[mt] = *(const short8*)&As[(wm * 64 + mt * 16 + lr) * 32 + kq * 8];
#pragma unroll
    for (int nt = 0; nt < 4; ++nt)
      b[nt] = *(const short8*)&Bs[(wn * 64 + nt * 16 + lr) * 32 + kq * 8];
#pragma unroll
    for (int mt = 0; mt < 4; ++mt)
#pragma unroll
      for (int nt = 0; nt < 4; ++nt)
        acc[mt][nt] = __builtin_amdgcn_mfma_f32_16x16x32_bf16(
            a[mt], b[nt], acc[mt][nt], 0, 0, 0);
    __syncthreads();
  }
#pragma unroll
  for (int mt = 0; mt < 4; ++mt)
#pragma unroll
    for (int nt = 0; nt < 4; ++nt)
#pragma unroll
      for (int r = 0; r < 4; ++r) {
        long row = m0 + wm * 64 + mt * 16 + kq * 4 + r;
        long col = n0 + wn * 64 + nt * 16 + lr;
        float v = acc[mt][nt][r];
        if (WRITE_BF16)
          ((bfu*)Cout)[row * N + col] = f2b(v);
        else
          ((float*)Cout)[row * N + col] = v;
      }
}

// ------ V transpose: KVb[B*NQ][8192] (V = cols 4096..8191) -> Vt[B*H][HD][NQ] --
__global__ void transpose_v(const bfu* __restrict__ KVb, bfu* __restrict__ Vt) {
  __shared__ bfu t[32][33];
  const int bh = blockIdx.z;
  const int tq = blockIdx.x;
  const int td = blockIdx.y;
  const int b = bh >> 5, h = bh & 31;
  const int tx = threadIdx.x & 31, ty = threadIdx.x >> 5;
  const bfu* src =
      KVb + ((long)(b * NQn + tq * 32)) * 8192 + 4096 + h * HDn + td * 32;
#pragma unroll
  for (int i = 0; i < 32; i += 8) t[ty + i][tx] = src[(long)(ty + i) * 8192 + tx];
  __syncthreads();
  bfu* dst = Vt + ((long)bh * HDn + td * 32) * NQn + tq * 32;
#pragma unroll
  for (int i = 0; i < 32; i += 8) dst[(long)(ty + i) * NQn + tx] = t[tx][ty + i];
}

// ========== fused attention (R9-verified flash-style, K from KVb) =============
__global__ __launch_bounds__(256, 3)
void attn_kernel(const bfu* __restrict__ Qb, const bfu* __restrict__ KVb,
                 const bfu* __restrict__ Vt, const float* __restrict__ mask,
                 bfu* __restrict__ AO) {
  __shared__ __align__(16) bfu Ks[2][4096];  // 2 x 8KB: [32 keys][128 d] swz
  __shared__ __align__(16) bfu Vs[2][4096];  // 2 x 8KB: [128 d][32 keys] lin
  const int bid = blockIdx.x;                // natural order (R2: no XCD swz)
  const int h = bid & (Hn - 1);
  const int b = (bid >> 5) & (Bn - 1);
  const int qt0 = bid >> 6;                  // [0,64)
  const long q0 = (long)qt0 * 64;
  const int tid = threadIdx.x;
  const int wave = tid >> 6, lane = tid & 63;
  const int lr = lane & 15, kq = lane >> 4;
  const float scale = 0.08838834764831845f;  // 1/sqrt(128)

  const long qrow = (long)b * Sn + q0 + wave * 16 + lr;
  const bfu* Kblk = KVb + (long)b * NQn * 8192 + h * HDn;  // K: stride 8192
  const bfu* Vblk = Vt + ((long)(b * Hn + h)) * HDn * NQn;
  const float* mrow = mask + ((long)b * Sn + q0 + wave * 16 + lr) * NQn;

  auto stageK = [&](int kt, int buf) {
#pragma unroll
    for (int i = 0; i < 2; ++i) {
      int c = i * 256 + tid;
      int j = c >> 4, c16 = c & 15;
      gload16(Kblk + (long)(kt * 32 + j) * 8192 + ((c16 ^ (j & 7)) * 8),
              &Ks[buf][(i * 256 + wave * 64) * 8]);
    }
  };
  auto stageV = [&](int kt, int buf) {
#pragma unroll
    for (int i = 0; i < 2; ++i) {
      int c = i * 256 + tid;
      int j = c >> 2, c4 = c & 3;
      gload16(Vblk + (long)j * NQn + kt * 32 + c4 * 8,
              &Vs[buf][(i * 256 + wave * 64) * 8]);
    }
  };

  stageK(0, 0);
  stageV(0, 0);

  const bfu* Qbase = Qb + qrow * HIDn + h * HDn;
  short8 qf[4];
#pragma unroll
  for (int ks = 0; ks < 4; ++ks)
    qf[ks] = *(const short8*)&Qbase[ks * 32 + kq * 8];

  f32x4 o[8] = {};
  float rsum = 0.f;

  for (int kt = 0; kt < 18; ++kt) {
    __syncthreads();
    const int buf = kt & 1;
    if (kt < 17) {
      stageK(kt + 1, buf ^ 1);
      stageV(kt + 1, buf ^ 1);
    }
    const char* kb = (const char*)Ks[buf];
    f32x4 s0 = {}, s1 = {};
#pragma unroll
    for (int ks = 0; ks < 4; ++ks) {
      short8 kf0 = *(const short8*)(kb + ((lr * 256 + ks * 64 + kq * 16) ^
                                          ((lr & 7) << 4)));
      short8 kf1 = *(const short8*)(kb + (((16 + lr) * 256 + ks * 64 + kq * 16) ^
                                          ((lr & 7) << 4)));
      s0 = __builtin_amdgcn_mfma_f32_16x16x32_bf16(kf0, qf[ks], s0, 0, 0, 0);
      s1 = __builtin_amdgcn_mfma_f32_16x16x32_bf16(kf1, qf[ks], s1, 0, 0, 0);
    }
    float4 m0 = *(const float4*)&mrow[kt * 32 + kq * 4];
    float4 m1 = *(const float4*)&mrow[kt * 32 + 16 + kq * 4];
    float p00 = __expf(s0[0] * scale + m0.x), p01 = __expf(s0[1] * scale + m0.y);
    float p02 = __expf(s0[2] * scale + m0.z), p03 = __expf(s0[3] * scale + m0.w);
    float p10 = __expf(s1[0] * scale + m1.x), p11 = __expf(s1[1] * scale + m1.y);
    float p12 = __expf(s1[2] * scale + m1.z), p13 = __expf(s1[3] * scale + m1.w);
    rsum += ((p00 + p01) + (p02 + p03)) + ((p10 + p11) + (p12 + p13));
    int pk0_0 = (int)((uint32_t)f2b(p00) | ((uint32_t)f2b(p01) << 16));
    int pk0_1 = (int)((uint32_t)f2b(p02) | ((uint32_t)f2b(p03) << 16));
    int pk1_0 = (int)((uint32_t)f2b(p10) | ((uint32_t)f2b(p11) << 16));
    int pk1_1 = (int)((uint32_t)f2b(p12) | ((uint32_t)f2b(p13) << 16));
    const int sLo = lr + (((kq & 1) << 1) << 4);
    const int sHi = sLo + 16;
    int b0, b1, b2, b3;
    {
      int v0 = __shfl(pk0_0, sLo, 64), v1 = __shfl(pk1_0, sLo, 64);
      b0 = (kq < 2) ? v0 : v1;
      v0 = __shfl(pk0_1, sLo, 64); v1 = __shfl(pk1_1, sLo, 64);
      b1 = (kq < 2) ? v0 : v1;
      v0 = __shfl(pk0_0, sHi, 64); v1 = __shfl(pk1_0, sHi, 64);
      b2 = (kq < 2) ? v0 : v1;
      v0 = __shfl(pk0_1, sHi, 64); v1 = __shfl(pk1_1, sHi, 64);
      b3 = (kq < 2) ? v0 : v1;
    }
    int4 pfi = {b0, b1, b2, b3};
    short8 pfrag = __builtin_bit_cast(short8, pfi);
    const char* vb = (const char*)Vs[buf];
#pragma unroll
    for (int dt = 0; dt < 8; ++dt) {
      short8 vf = *(const short8*)(vb + ((dt * 16 + lr) * 64 + kq * 16));
      o[dt] = __builtin_amdgcn_mfma_f32_16x16x32_bf16(vf, pfrag, o[dt], 0, 0, 0);
    }
  }

  rsum += __shfl_xor(rsum, 16, 64);
  rsum += __shfl_xor(rsum, 32, 64);
  const float inv = 1.0f / rsum;

  bfu* Obase = AO + qrow * HIDn + h * HDn;
#pragma unroll
  for (int dt = 0; dt < 8; ++dt) {
    uint64_t pk = (uint64_t)f2b(o[dt][0] * inv) |
                  ((uint64_t)f2b(o[dt][1] * inv) << 16) |
                  ((uint64_t)f2b(o[dt][2] * inv) << 32) |
                  ((uint64_t)f2b(o[dt][3] * inv) << 48);
    *(uint64_t*)&Obase[dt * 16 + kq * 4] = pk;
  }
}

// ------------------------------- launcher --------------------------------------
extern "C" void kernel_launch(void* const* d_in, const int* in_sizes, int n_in,
                              void* d_out, int out_size, void* d_ws, size_t ws_size,
                              hipStream_t stream) {
  const float* hs = (const float*)d_in[0];
  const float* bp = (const float*)d_in[1];
  const float* mask = (const float*)d_in[2];
  const float* Wq = (const float*)d_in[3];
  const float* Wk = (const float*)d_in[4];
  const float* Wv = (const float*)d_in[5];
  const float* Wo = (const float*)d_in[6];
  float* out = (float*)d_out;

  const long M1 = (long)Bn * Sn;   // 8192
  const long M2 = (long)Bn * NQn;  // 1152
  char* ws = (char*)d_ws;
  bfu* hb = (bfu*)(ws + 0);                  // 67,108,864  (also AO)
  bfu* bb = (bfu*)(ws + 67108864);           //  9,437,184
  bfu* w1 = (bfu*)(ws + 76546048);           // 33,554,432  (Wq, later Wo)
  bfu* wkv = (bfu*)(ws + 110100480);         // 67,108,864  (Wk rows 0-4095,
                                             //              Wv rows 4096-8191)
  bfu* Qb = (bfu*)(ws + 177209344);          // 67,108,864
  bfu* KVb = (bfu*)(ws + 244318208);         // 18,874,368  [1152][8192]
  bfu* Vt = (bfu*)(ws + 263192576);          //  9,437,184  -> total 272,629,760

  auto cast = [&](const float* src, bfu* dst, long n) {
    int n8 = (int)(n / 8);
    cast_f32_bf16<<<dim3((n8 + 255) / 256), dim3(256), 0, stream>>>(src, dst, n8);
  };
  cast(hs, hb, M1 * HIDn);
  cast(bp, bb, M2 * HIDn);
  cast(Wq, w1, (long)HIDn * HIDn);
  cast(Wk, wkv, (long)HIDn * HIDn);
  cast(Wv, wkv + (long)HIDn * HIDn, (long)HIDn * HIDn);

  gemm_bt256<1><<<dim3(HIDn / 256, M1 / 256), dim3(512), 0, stream>>>(
      hb, w1, Qb, (int)M1, HIDn, HIDn);
  // batched K+V projection: C[1152][8192] = bb @ [Wk;Wv]^T  (one dispatch)
  gemm_bt<1><<<dim3(8192 / 128, M2 / 128), dim3(256), 0, stream>>>(
      bb, wkv, KVb, (int)M2, 8192, HIDn);

  cast(Wo, w1, (long)HIDn * HIDn);  // w1 slot free after Q-proj
  transpose_v<<<dim3(NQn / 32, HDn / 32, Bn * Hn), dim3(256), 0, stream>>>(
      KVb, Vt);

  attn_kernel<<<dim3((Sn / 64) * Bn * Hn), dim3(256), 0, stream>>>(
      Qb, KVb, Vt, mask, hb /*AO aliases hb*/);

  gemm_bt256<0><<<dim3(HIDn / 256, M1 / 256), dim3(512), 0, stream>>>(
      hb, w1, out, (int)M1, HIDn, HIDn);
}

// Round 11
// 902.668 us; speedup vs baseline: 1.5743x; 1.0538x over previous
//
#include <hip/hip_runtime.h>
#include <stdint.h>

// Problem constants
#define Bn   2
#define Sn   4096
#define NQn  576
#define Hn   32
#define HDn  128
#define HIDn 4096

typedef unsigned short bfu;  // raw bf16 bits
typedef short short8 __attribute__((ext_vector_type(8)));
typedef float f32x4 __attribute__((ext_vector_type(4)));

__device__ __forceinline__ bfu f2b(float f) {
  uint32_t x = __builtin_bit_cast(uint32_t, f);
  return (bfu)((x + 0x7fffu + ((x >> 16) & 1u)) >> 16);  // RNE
}

__device__ __forceinline__ void gload16(const void* g, void* l) {
  // async global->LDS, 16B per lane; LDS dest = wave-uniform base + lane*16
  __builtin_amdgcn_global_load_lds(
      (const __attribute__((address_space(1))) uint32_t*)g,
      (__attribute__((address_space(3))) uint32_t*)l, 16, 0, 0);
}

// ---------------- cast f32 -> bf16 (vectorized: 2x float4 in, 16B out) ---------
__global__ void cast_f32_bf16(const float* __restrict__ in, bfu* __restrict__ out,
                              int n8) {
  int i = blockIdx.x * 256 + threadIdx.x;
  if (i >= n8) return;
  const float4* in4 = (const float4*)in;
  float4 a = in4[2 * i], c = in4[2 * i + 1];
  short8 v;
  v[0] = (short)f2b(a.x); v[1] = (short)f2b(a.y);
  v[2] = (short)f2b(a.z); v[3] = (short)f2b(a.w);
  v[4] = (short)f2b(c.x); v[5] = (short)f2b(c.y);
  v[6] = (short)f2b(c.z); v[7] = (short)f2b(c.w);
  ((short8*)out)[i] = v;
}

// ======== 256^2 whole-tile-pipelined GEMM (R8-verified): C = A @ Bm^T =========
// R10 post-mortem: 32x32x16 variant created 2.5e7 bank conflicts (my phase-
// group conflict model was wrong) and regressed 303->326us. REVERTED to this
// R8-exact version: 16x16x32, whole-tile double-buffer (stage all of t+1 at
// top of tile t; full-tile prefetch lead ~2800cy >> 900cy HBM latency so the
// boundary vmcnt(0) is free), 0 measured conflicts, 303us / ~907 TF.
// This is the plain-HIP structural plateau (m97-family); two schedule attempts
// (R7 4-phase lockstep 37.7%, R8 39.1%) land within noise of each other.
template <int WRITE_BF16>
__global__ __launch_bounds__(512, 2)
void gemm_bt256(const bfu* __restrict__ A, const bfu* __restrict__ Bm,
                void* __restrict__ Cout, int M, int N, int K) {
  __shared__ __align__(16) bfu Asm[2][256 * 64];  // 32KB per buffer
  __shared__ __align__(16) bfu Bsm[2][256 * 64];
  const int tid = threadIdx.x;
  const int wave = tid >> 6, lane = tid & 63;
  const int lr = lane & 15, kq = lane >> 4;
  const int wm = wave >> 2, wn = wave & 3;  // 2 x 4 wave grid
  const long m0 = (long)blockIdx.y * 256, n0 = (long)blockIdx.x * 256;
  const int NT = K >> 6;  // K-tiles of 64

  const int c0j = tid >> 3, c0c = tid & 7;
  const int c1j = (512 + tid) >> 3, c1c = tid & 7;
  const bfu* aSrc0 = A + (m0 + c0j) * (long)K + ((c0c ^ (c0j & 7)) * 8);
  const bfu* aSrc1 = A + (m0 + c1j) * (long)K + ((c1c ^ (c1j & 7)) * 8);
  const bfu* bSrc0 = Bm + (n0 + c0j) * (long)K + ((c0c ^ (c0j & 7)) * 8);
  const bfu* bSrc1 = Bm + (n0 + c1j) * (long)K + ((c1c ^ (c1j & 7)) * 8);

  auto stageA = [&](int t, int buf, int half) {
    long koff = (long)t * 64 + (long)half * 128 * K;
    gload16(aSrc0 + koff, &Asm[buf][half * 8192 + (wave * 64) * 8]);
    gload16(aSrc1 + koff, &Asm[buf][half * 8192 + (512 + wave * 64) * 8]);
  };
  auto stageB = [&](int t, int buf, int half) {
    long koff = (long)t * 64 + (long)half * 128 * K;
    gload16(bSrc0 + koff, &Bsm[buf][half * 8192 + (wave * 64) * 8]);
    gload16(bSrc1 + koff, &Bsm[buf][half * 8192 + (512 + wave * 64) * 8]);
  };
  auto ldsA = [&](int buf, int mf, int ks) -> short8 {
    int row = (mf >> 2) * 128 + wm * 64 + (mf & 3) * 16 + lr;
    int off = (row * 128 + ks * 64 + kq * 16) ^ ((row & 7) << 4);
    return *(const short8*)((const char*)Asm[buf] + off);
  };
  auto ldsB = [&](int buf, int nf, int ks) -> short8 {
    int row = (nf >> 1) * 128 + wn * 32 + (nf & 1) * 16 + lr;
    int off = (row * 128 + ks * 64 + kq * 16) ^ ((row & 7) << 4);
    return *(const short8*)((const char*)Bsm[buf] + off);
  };

  f32x4 acc[8][4] = {};

  stageA(0, 0, 0); stageB(0, 0, 0); stageB(0, 0, 1); stageA(0, 0, 1);
  asm volatile("s_waitcnt vmcnt(0)" ::: "memory");
  __builtin_amdgcn_s_barrier();

  for (int t = 0; t < NT; ++t) {
    const int buf = t & 1;
    if (t + 1 < NT) {
      stageA(t + 1, buf ^ 1, 0);
      stageB(t + 1, buf ^ 1, 0);
      stageB(t + 1, buf ^ 1, 1);
      stageA(t + 1, buf ^ 1, 1);
    }
    short8 a0[4][2], a1[4][2], b0[2][2], b1[2][2];
#pragma unroll
    for (int mf = 0; mf < 4; ++mf) {
      a0[mf][0] = ldsA(buf, mf, 0);
      a0[mf][1] = ldsA(buf, mf, 1);
    }
#pragma unroll
    for (int nf = 0; nf < 2; ++nf) {
      b0[nf][0] = ldsB(buf, nf, 0);
      b0[nf][1] = ldsB(buf, nf, 1);
      b1[nf][0] = ldsB(buf, 2 + nf, 0);
      b1[nf][1] = ldsB(buf, 2 + nf, 1);
    }
#pragma unroll
    for (int mf = 0; mf < 4; ++mf)
#pragma unroll
      for (int ks = 0; ks < 2; ++ks)
#pragma unroll
        for (int nf = 0; nf < 2; ++nf)
          acc[mf][nf] = __builtin_amdgcn_mfma_f32_16x16x32_bf16(
              a0[mf][ks], b0[nf][ks], acc[mf][nf], 0, 0, 0);
#pragma unroll
    for (int mf = 0; mf < 4; ++mf) {
      a1[mf][0] = ldsA(buf, 4 + mf, 0);
      a1[mf][1] = ldsA(buf, 4 + mf, 1);
    }
#pragma unroll
    for (int mf = 0; mf < 4; ++mf)
#pragma unroll
      for (int ks = 0; ks < 2; ++ks)
#pragma unroll
        for (int nf = 0; nf < 2; ++nf)
          acc[mf][2 + nf] = __builtin_amdgcn_mfma_f32_16x16x32_bf16(
              a0[mf][ks], b1[nf][ks], acc[mf][2 + nf], 0, 0, 0);
#pragma unroll
    for (int mf = 0; mf < 4; ++mf)
#pragma unroll
      for (int ks = 0; ks < 2; ++ks)
#pragma unroll
        for (int nf = 0; nf < 2; ++nf)
          acc[4 + mf][2 + nf] = __builtin_amdgcn_mfma_f32_16x16x32_bf16(
              a1[mf][ks], b1[nf][ks], acc[4 + mf][2 + nf], 0, 0, 0);
#pragma unroll
    for (int mf = 0; mf < 4; ++mf)
#pragma unroll
      for (int ks = 0; ks < 2; ++ks)
#pragma unroll
        for (int nf = 0; nf < 2; ++nf)
          acc[4 + mf][nf] = __builtin_amdgcn_mfma_f32_16x16x32_bf16(
              a1[mf][ks], b0[nf][ks], acc[4 + mf][nf], 0, 0, 0);
    asm volatile("s_waitcnt vmcnt(0)" ::: "memory");
    __builtin_amdgcn_s_barrier();
  }

#pragma unroll
  for (int mf = 0; mf < 8; ++mf)
#pragma unroll
    for (int nf = 0; nf < 4; ++nf)
#pragma unroll
      for (int r = 0; r < 4; ++r) {
        long row = m0 + (mf >> 2) * 128 + wm * 64 + (mf & 3) * 16 + kq * 4 + r;
        long col = n0 + (nf >> 1) * 128 + wn * 32 + (nf & 1) * 16 + lr;
        float v = acc[mf][nf][r];
        if (WRITE_BF16)
          ((bfu*)Cout)[row * N + col] = f2b(v);
        else
          ((float*)Cout)[row * N + col] = v;
      }
}

// ---------------- GEMM: 128^2 m97-style (batched K/V projection) --------------
template <int WRITE_BF16>
__global__ __launch_bounds__(256, 2)
void gemm_bt(const bfu* __restrict__ A, const bfu* __restrict__ Bm,
             void* __restrict__ Cout, int M, int N, int K) {
  __shared__ __align__(16) bfu As[128 * 32];
  __shared__ __align__(16) bfu Bs[128 * 32];
  const int tid = threadIdx.x;
  const int wave = tid >> 6, lane = tid & 63;
  const int lr = lane & 15, kq = lane >> 4;
  const int wm = wave >> 1, wn = wave & 1;
  const long m0 = (long)blockIdx.y * 128, n0 = (long)blockIdx.x * 128;

  f32x4 acc[4][4] = {};

  for (int kk = 0; kk < K; kk += 32) {
#pragma unroll
    for (int i = 0; i < 2; ++i) {
      int tt = i * 256 + tid;
      long row = tt >> 2;
      int col = (tt & 3) * 8;
      gload16(A + (m0 + row) * K + kk + col, &As[(i * 256 + wave * 64) * 8]);
      gload16(Bm + (n0 + row) * K + kk + col, &Bs[(i * 256 + wave * 64) * 8]);
    }
    __syncthreads();
    short8 a[4], b[4];
#pragma unroll
    for (int mt = 0; mt < 4; ++mt)
      a[mt] = *(const short8*)&As[(wm * 64 + mt * 16 + lr) * 32 + kq * 8];
#pragma unroll
    for (int nt = 0; nt < 4; ++nt)
      b[nt] = *(const short8*)&Bs[(wn * 64 + nt * 16 + lr) * 32 + kq * 8];
#pragma unroll
    for (int mt = 0; mt < 4; ++mt)
#pragma unroll
      for (int nt = 0; nt < 4; ++nt)
        acc[mt][nt] = __builtin_amdgcn_mfma_f32_16x16x32_bf16(
            a[mt], b[nt], acc[mt][nt], 0, 0, 0);
    __syncthreads();
  }
#pragma unroll
  for (int mt = 0; mt < 4; ++mt)
#pragma unroll
    for (int nt = 0; nt < 4; ++nt)
#pragma unroll
      for (int r = 0; r < 4; ++r) {
        long row = m0 + wm * 64 + mt * 16 + kq * 4 + r;
        long col = n0 + wn * 64 + nt * 16 + lr;
        float v = acc[mt][nt][r];
        if (WRITE_BF16)
          ((bfu*)Cout)[row * N + col] = f2b(v);
        else
          ((float*)Cout)[row * N + col] = v;
      }
}

// ------ V transpose: KVb[B*NQ][8192] (V = cols 4096..8191) -> Vt[B*H][HD][NQ] --
__global__ void transpose_v(const bfu* __restrict__ KVb, bfu* __restrict__ Vt) {
  __shared__ bfu t[32][33];
  const int bh = blockIdx.z;
  const int tq = blockIdx.x;
  const int td = blockIdx.y;
  const int b = bh >> 5, h = bh & 31;
  const int tx = threadIdx.x & 31, ty = threadIdx.x >> 5;
  const bfu* src =
      KVb + ((long)(b * NQn + tq * 32)) * 8192 + 4096 + h * HDn + td * 32;
#pragma unroll
  for (int i = 0; i < 32; i += 8) t[ty + i][tx] = src[(long)(ty + i) * 8192 + tx];
  __syncthreads();
  bfu* dst = Vt + ((long)bh * HDn + td * 32) * NQn + tq * 32;
#pragma unroll
  for (int i = 0; i < 32; i += 8) dst[(long)(ty + i) * NQn + tx] = t[tx][ty + i];
}

// ========== fused attention (R9-verified flash-style, K from KVb) =============
// R11: launch_bounds min-waves 3 -> 4 (LDS 33KB x 4 = 132KB fits) for an
// extra block/CU of cross-block phase diversity in the 18-round barrier loop.
__global__ __launch_bounds__(256, 4)
void attn_kernel(const bfu* __restrict__ Qb, const bfu* __restrict__ KVb,
                 const bfu* __restrict__ Vt, const float* __restrict__ mask,
                 bfu* __restrict__ AO) {
  __shared__ __align__(16) bfu Ks[2][4096];  // 2 x 8KB: [32 keys][128 d] swz
  __shared__ __align__(16) bfu Vs[2][4096];  // 2 x 8KB: [128 d][32 keys] lin
  const int bid = blockIdx.x;                // natural order (R2: no XCD swz)
  const int h = bid & (Hn - 1);
  const int b = (bid >> 5) & (Bn - 1);
  const int qt0 = bid >> 6;                  // [0,64)
  const long q0 = (long)qt0 * 64;
  const int tid = threadIdx.x;
  const int wave = tid >> 6, lane = tid & 63;
  const int lr = lane & 15, kq = lane >> 4;
  const float scale = 0.08838834764831845f;  // 1/sqrt(128)

  const long qrow = (long)b * Sn + q0 + wave * 16 + lr;
  const bfu* Kblk = KVb + (long)b * NQn * 8192 + h * HDn;  // K: stride 8192
  const bfu* Vblk = Vt + ((long)(b * Hn + h)) * HDn * NQn;
  const float* mrow = mask + ((long)b * Sn + q0 + wave * 16 + lr) * NQn;

  auto stageK = [&](int kt, int buf) {
#pragma unroll
    for (int i = 0; i < 2; ++i) {
      int c = i * 256 + tid;
      int j = c >> 4, c16 = c & 15;
      gload16(Kblk + (long)(kt * 32 + j) * 8192 + ((c16 ^ (j & 7)) * 8),
              &Ks[buf][(i * 256 + wave * 64) * 8]);
    }
  };
  auto stageV = [&](int kt, int buf) {
#pragma unroll
    for (int i = 0; i < 2; ++i) {
      int c = i * 256 + tid;
      int j = c >> 2, c4 = c & 3;
      gload16(Vblk + (long)j * NQn + kt * 32 + c4 * 8,
              &Vs[buf][(i * 256 + wave * 64) * 8]);
    }
  };

  stageK(0, 0);
  stageV(0, 0);

  const bfu* Qbase = Qb + qrow * HIDn + h * HDn;
  short8 qf[4];
#pragma unroll
  for (int ks = 0; ks < 4; ++ks)
    qf[ks] = *(const short8*)&Qbase[ks * 32 + kq * 8];

  f32x4 o[8] = {};
  float rsum = 0.f;

  for (int kt = 0; kt < 18; ++kt) {
    __syncthreads();
    const int buf = kt & 1;
    if (kt < 17) {
      stageK(kt + 1, buf ^ 1);
      stageV(kt + 1, buf ^ 1);
    }
    const char* kb = (const char*)Ks[buf];
    f32x4 s0 = {}, s1 = {};
#pragma unroll
    for (int ks = 0; ks < 4; ++ks) {
      short8 kf0 = *(const short8*)(kb + ((lr * 256 + ks * 64 + kq * 16) ^
                                          ((lr & 7) << 4)));
      short8 kf1 = *(const short8*)(kb + (((16 + lr) * 256 + ks * 64 + kq * 16) ^
                                          ((lr & 7) << 4)));
      s0 = __builtin_amdgcn_mfma_f32_16x16x32_bf16(kf0, qf[ks], s0, 0, 0, 0);
      s1 = __builtin_amdgcn_mfma_f32_16x16x32_bf16(kf1, qf[ks], s1, 0, 0, 0);
    }
    float4 m0 = *(const float4*)&mrow[kt * 32 + kq * 4];
    float4 m1 = *(const float4*)&mrow[kt * 32 + 16 + kq * 4];
    float p00 = __expf(s0[0] * scale + m0.x), p01 = __expf(s0[1] * scale + m0.y);
    float p02 = __expf(s0[2] * scale + m0.z), p03 = __expf(s0[3] * scale + m0.w);
    float p10 = __expf(s1[0] * scale + m1.x), p11 = __expf(s1[1] * scale + m1.y);
    float p12 = __expf(s1[2] * scale + m1.z), p13 = __expf(s1[3] * scale + m1.w);
    rsum += ((p00 + p01) + (p02 + p03)) + ((p10 + p11) + (p12 + p13));
    int pk0_0 = (int)((uint32_t)f2b(p00) | ((uint32_t)f2b(p01) << 16));
    int pk0_1 = (int)((uint32_t)f2b(p02) | ((uint32_t)f2b(p03) << 16));
    int pk1_0 = (int)((uint32_t)f2b(p10) | ((uint32_t)f2b(p11) << 16));
    int pk1_1 = (int)((uint32_t)f2b(p12) | ((uint32_t)f2b(p13) << 16));
    const int sLo = lr + (((kq & 1) << 1) << 4);
    const int sHi = sLo + 16;
    int b0, b1, b2, b3;
    {
      int v0 = __shfl(pk0_0, sLo, 64), v1 = __shfl(pk1_0, sLo, 64);
      b0 = (kq < 2) ? v0 : v1;
      v0 = __shfl(pk0_1, sLo, 64); v1 = __shfl(pk1_1, sLo, 64);
      b1 = (kq < 2) ? v0 : v1;
      v0 = __shfl(pk0_0, sHi, 64); v1 = __shfl(pk1_0, sHi, 64);
      b2 = (kq < 2) ? v0 : v1;
      v0 = __shfl(pk0_1, sHi, 64); v1 = __shfl(pk1_1, sHi, 64);
      b3 = (kq < 2) ? v0 : v1;
    }
    int4 pfi = {b0, b1, b2, b3};
    short8 pfrag = __builtin_bit_cast(short8, pfi);
    const char* vb = (const char*)Vs[buf];
#pragma unroll
    for (int dt = 0; dt < 8; ++dt) {
      short8 vf = *(const short8*)(vb + ((dt * 16 + lr) * 64 + kq * 16));
      o[dt] = __builtin_amdgcn_mfma_f32_16x16x32_bf16(vf, pfrag, o[dt], 0, 0, 0);
    }
  }

  rsum += __shfl_xor(rsum, 16, 64);
  rsum += __shfl_xor(rsum, 32, 64);
  const float inv = 1.0f / rsum;

  bfu* Obase = AO + qrow * HIDn + h * HDn;
#pragma unroll
  for (int dt = 0; dt < 8; ++dt) {
    uint64_t pk = (uint64_t)f2b(o[dt][0] * inv) |
                  ((uint64_t)f2b(o[dt][1] * inv) << 16) |
                  ((uint64_t)f2b(o[dt][2] * inv) << 32) |
                  ((uint64_t)f2b(o[dt][3] * inv) << 48);
    *(uint64_t*)&Obase[dt * 16 + kq * 4] = pk;
  }
}

// ------------------------------- launcher --------------------------------------
extern "C" void kernel_launch(void* const* d_in, const int* in_sizes, int n_in,
                              void* d_out, int out_size, void* d_ws, size_t ws_size,
                              hipStream_t stream) {
  const float* hs = (const float*)d_in[0];
  const float* bp = (const float*)d_in[1];
  const float* mask = (const float*)d_in[2];
  const float* Wq = (const float*)d_in[3];
  const float* Wk = (const float*)d_in[4];
  const float* Wv = (const float*)d_in[5];
  const float* Wo = (const float*)d_in[6];
  float* out = (float*)d_out;

  const long M1 = (long)Bn * Sn;   // 8192
  const long M2 = (long)Bn * NQn;  // 1152
  char* ws = (char*)d_ws;
  bfu* hb = (bfu*)(ws + 0);                  // 67,108,864  (also AO)
  bfu* bb = (bfu*)(ws + 67108864);           //  9,437,184
  bfu* w1 = (bfu*)(ws + 76546048);           // 33,554,432  (Wq, later Wo)
  bfu* wkv = (bfu*)(ws + 110100480);         // 67,108,864  (Wk rows 0-4095,
                                             //              Wv rows 4096-8191)
  bfu* Qb = (bfu*)(ws + 177209344);          // 67,108,864
  bfu* KVb = (bfu*)(ws + 244318208);         // 18,874,368  [1152][8192]
  bfu* Vt = (bfu*)(ws + 263192576);          //  9,437,184  -> total 272,629,760

  auto cast = [&](const float* src, bfu* dst, long n) {
    int n8 = (int)(n / 8);
    cast_f32_bf16<<<dim3((n8 + 255) / 256), dim3(256), 0, stream>>>(src, dst, n8);
  };
  cast(hs, hb, M1 * HIDn);
  cast(bp, bb, M2 * HIDn);
  cast(Wq, w1, (long)HIDn * HIDn);
  cast(Wk, wkv, (long)HIDn * HIDn);
  cast(Wv, wkv + (long)HIDn * HIDn, (long)HIDn * HIDn);

  gemm_bt256<1><<<dim3(HIDn / 256, M1 / 256), dim3(512), 0, stream>>>(
      hb, w1, Qb, (int)M1, HIDn, HIDn);
  // batched K+V projection: C[1152][8192] = bb @ [Wk;Wv]^T  (one dispatch)
  gemm_bt<1><<<dim3(8192 / 128, M2 / 128), dim3(256), 0, stream>>>(
      bb, wkv, KVb, (int)M2, 8192, HIDn);

  cast(Wo, w1, (long)HIDn * HIDn);  // w1 slot free after Q-proj
  transpose_v<<<dim3(NQn / 32, HDn / 32, Bn * Hn), dim3(256), 0, stream>>>(
      KVb, Vt);

  attn_kernel<<<dim3((Sn / 64) * Bn * Hn), dim3(256), 0, stream>>>(
      Qb, KVb, Vt, mask, hb /*AO aliases hb*/);

  gemm_bt256<0><<<dim3(HIDn / 256, M1 / 256), dim3(512), 0, stream>>>(
      hb, w1, out, (int)M1, HIDn, HIDn);
}